// Round 1
// baseline (2816.000 us; speedup 1.0000x reference)
//
#include <hip/hip_runtime.h>
#include <math.h>

#define MU1  256
#define H    64
#define H2   128
#define SKIPC 256
#define NL   24
#define LF   80
#define UPK  4
#define REP  75
#define BB   2
#define LLEN 64
#define LL   19200   // SLEN
#define TT   64      // layer-kernel time tile
#define TT2  16      // head time tile

// ---------------------------------------------------------------- prep ----
// Transpose all weight matrices so inner-loop reads are lane-coalesced.
__global__ __launch_bounds__(256) void prep_kernel(
    const float* __restrict__ dil_W,  const float* __restrict__ skip_W,
    const float* __restrict__ res_W,  const float* __restrict__ embed_W,
    const float* __restrict__ cond_W, const float* __restrict__ out_W1,
    const float* __restrict__ out_W2,
    float* __restrict__ dil_Wt, float* __restrict__ skip_Wt,
    float* __restrict__ res_Wt, float* __restrict__ embed_Wt,
    float* __restrict__ cond_Wt, float* __restrict__ W1t, float* __restrict__ W2t)
{
    int idx = blockIdx.x * 256 + threadIdx.x;
    const int n1 = NL * 2 * H * H2;     // 393216 dil_Wt[i][k][c][o]
    const int n2 = NL * H * SKIPC;      // 393216 skip_Wt[i][h][s]
    const int n3 = (NL - 1) * H * H;    //  94208 res_Wt[i][h][c]
    const int n4 = MU1 * H;             //  16384 embed_Wt[g][h]
    const int n5 = LF * NL * H2;        // 245760 cond_Wt[c][o]
    const int n6 = MU1 * SKIPC;         //  65536 W1t[c][o]
    const int n7 = MU1 * MU1;           //  65536 W2t[c][o]
    if (idx < n1) {
        int o = idx % H2; int c = (idx / H2) % H;
        int k = (idx / (H2 * H)) % 2; int i = idx / (H2 * H * 2);
        dil_Wt[idx] = dil_W[((i * H2 + o) * H + c) * 2 + k];
        return;
    }
    idx -= n1;
    if (idx < n2) {
        int s = idx % SKIPC; int h = (idx / SKIPC) % H; int i = idx / (SKIPC * H);
        skip_Wt[idx] = skip_W[(i * SKIPC + s) * H + h];
        return;
    }
    idx -= n2;
    if (idx < n3) {
        int c = idx % H; int h = (idx / H) % H; int i = idx / (H * H);
        res_Wt[idx] = res_W[(i * H + c) * H + h];
        return;
    }
    idx -= n3;
    if (idx < n4) {
        int h = idx % H; int g = idx / H;
        embed_Wt[idx] = embed_W[h * MU1 + g];
        return;
    }
    idx -= n4;
    if (idx < n5) {
        int o = idx % (NL * H2); int c = idx / (NL * H2);
        cond_Wt[idx] = cond_W[o * LF + c];
        return;
    }
    idx -= n5;
    if (idx < n6) {
        int o = idx % MU1; int c = idx / MU1;
        W1t[idx] = out_W1[o * SKIPC + c];
        return;
    }
    idx -= n6;
    if (idx < n7) {
        int o = idx % MU1; int c = idx / MU1;
        W2t[idx] = out_W2[o * MU1 + c];
        return;
    }
}

// --------------------------------------------------------------- embed ----
__global__ __launch_bounds__(256) void embed_kernel(
    const int* __restrict__ gold, const float* __restrict__ embed_Wt,
    const float* __restrict__ embed_b, float* __restrict__ sig)
{
    int idx = blockIdx.x * 256 + threadIdx.x;
    if (idx >= BB * LL * H) return;
    int h = idx % H;
    int bt = idx / H;
    int g = gold[bt];
    sig[idx] = embed_Wt[g * H + h] + embed_b[h];
}

// ---------------------------------------------------------------- cond ----
// 256 distinct cond columns per batch (upsample frame*4+k, each repeated 75x)
__global__ __launch_bounds__(256) void cond_kernel(
    const float* __restrict__ lf, const float* __restrict__ up_W,
    const float* __restrict__ up_b, const float* __restrict__ cond_Wt,
    const float* __restrict__ cond_b, float* __restrict__ cond_small)
{
    __shared__ float s_up[LF];
    int b = blockIdx.y;
    int j = blockIdx.x;            // 0..255
    int frame = j >> 2, k = j & 3;
    int tid = threadIdx.x;
    if (tid < LF) {
        float acc = up_b[tid];
        const float* lfrow = lf + (b * LLEN + frame) * LF;
        for (int ci = 0; ci < LF; ci++)
            acc += lfrow[ci] * up_W[(ci * LF + tid) * UPK + k];
        s_up[tid] = acc;
    }
    __syncthreads();
    float* dst = cond_small + ((size_t)(b * 256 + j)) * (NL * H2);
    for (int r = 0; r < (NL * H2) / 256; r++) {
        int o = r * 256 + tid;
        float acc = cond_b[o];
        for (int c = 0; c < LF; c++)
            acc += cond_Wt[c * (NL * H2) + o] * s_up[c];
        dst[o] = acc;
    }
}

// --------------------------------------------------------------- layer ----
template<bool FIRST, bool LAST>
__global__ __launch_bounds__(256) void layer_kernel(
    const float* __restrict__ sig_in, float* __restrict__ sig_out,
    float* __restrict__ skip_sum,
    const float* __restrict__ dWt,      // [2][64][128] this layer
    const float* __restrict__ db,       // [128]
    const float* __restrict__ cond_small,
    int cond_off,                       // i*128
    const float* __restrict__ rWt,      // [64][64]
    const float* __restrict__ rb,       // [64]
    const float* __restrict__ sWt,      // [64][256]
    const float* __restrict__ sb_,      // [256]
    int d)
{
    __shared__ float s_cur[TT][H];
    __shared__ float s_prv[TT][H];
    __shared__ float s_z[TT][H];

    int b = blockIdx.y;
    int t0 = blockIdx.x * TT;
    int tid = threadIdx.x;
    const float* base = sig_in + (size_t)b * LL * H;
    int base_off = t0 * H;

    // phase 1: stage current + dilation-shifted rows (contiguous copies)
    for (int idx = tid; idx < TT * H; idx += 256) {
        ((float*)s_cur)[idx] = base[base_off + idx];
        int pi = base_off - d * H + idx;
        ((float*)s_prv)[idx] = (pi >= 0) ? base[pi] : 0.0f;
    }
    __syncthreads();

    // phase 2: gated activation  z = tanh(af)*sigmoid(ag)
    {
        int h = tid & 63;
        int tg = tid >> 6;              // 4 groups x 16 timesteps
        float accF[16], accG[16];
        #pragma unroll
        for (int j = 0; j < 16; j++) { accF[j] = 0.f; accG[j] = 0.f; }
        const float* W0 = dWt;          // k=0 taps prev
        const float* W1 = dWt + H * H2; // k=1 taps cur
        for (int c = 0; c < H; c++) {
            float wf0 = W0[c * H2 + h];
            float wg0 = W0[c * H2 + 64 + h];
            float wf1 = W1[c * H2 + h];
            float wg1 = W1[c * H2 + 64 + h];
            #pragma unroll
            for (int j = 0; j < 16; j++) {
                int t = tg * 16 + j;
                float p = s_prv[t][c];
                float s = s_cur[t][c];
                accF[j] += wf0 * p + wf1 * s;
                accG[j] += wg0 * p + wg1 * s;
            }
        }
        float bf = db[h], bg = db[64 + h];
        #pragma unroll
        for (int j = 0; j < 16; j++) {
            int t = tg * 16 + j;
            int col = (t0 + t) / REP;
            const float* crow = cond_small + ((size_t)(b * 256 + col)) * (NL * H2) + cond_off;
            float af = accF[j] + bf + crow[h];
            float ag = accG[j] + bg + crow[64 + h];
            float zz = tanhf(af) * (1.0f / (1.0f + __expf(-ag)));
            s_z[t][h] = zz;
        }
    }
    __syncthreads();

    // phase 3: residual update (skipped on last layer)
    if (!LAST) {
        int c = tid & 63;
        int tg = tid >> 6;
        float acc[16];
        float rbv = rb[c];
        #pragma unroll
        for (int j = 0; j < 16; j++) acc[j] = rbv;
        for (int hh = 0; hh < H; hh++) {
            float w = rWt[hh * H + c];
            #pragma unroll
            for (int j = 0; j < 16; j++) acc[j] += w * s_z[tg * 16 + j][hh];
        }
        float* outb = sig_out + (size_t)b * LL * H + base_off;
        #pragma unroll
        for (int j = 0; j < 16; j++) {
            int t = tg * 16 + j;
            outb[t * H + c] = s_cur[t][c] + acc[j];
        }
    }

    // phase 4: skip accumulation (RMW in global, FIRST layer writes)
    {
        int s = tid;                    // 0..255 skip channel
        float sbv = sb_[s];
        float* srow = skip_sum + ((size_t)b * LL + t0) * SKIPC;
        for (int ch = 0; ch < 4; ch++) {
            float acc[16];
            #pragma unroll
            for (int j = 0; j < 16; j++) acc[j] = sbv;
            for (int hh = 0; hh < H; hh++) {
                float w = sWt[hh * SKIPC + s];
                #pragma unroll
                for (int j = 0; j < 16; j++) acc[j] += w * s_z[ch * 16 + j][hh];
            }
            #pragma unroll
            for (int j = 0; j < 16; j++) {
                int t = ch * 16 + j;
                if (FIRST) srow[t * SKIPC + s] = acc[j];
                else       srow[t * SKIPC + s] += acc[j];
            }
        }
    }
}

// ---------------------------------------------------------------- head ----
__global__ __launch_bounds__(256) void head_kernel(
    const float* __restrict__ skip_sum,
    const float* __restrict__ W1t, const float* __restrict__ W2t,
    float* __restrict__ out)
{
    __shared__ float s_a[MU1];
    __shared__ float s_b[MU1];
    __shared__ float s_red[8];
    __shared__ float s_outT[TT2][MU1];

    int b = blockIdx.y;
    int t0 = blockIdx.x * TT2;
    int tid = threadIdx.x;
    int lane = tid & 63, wid = tid >> 6;

    for (int j = 0; j < TT2; j++) {
        int t = t0 + j;
        float v = skip_sum[((size_t)b * LL + t) * SKIPC + tid];
        s_a[tid] = fmaxf(v, 0.0f);
        __syncthreads();
        float acc = 0.f;
        for (int c = 0; c < SKIPC; c++) acc += W1t[c * MU1 + tid] * s_a[c];
        s_b[tid] = fmaxf(acc, 0.0f);
        __syncthreads();
        float lg = 0.f;
        for (int c = 0; c < MU1; c++) lg += W2t[c * MU1 + tid] * s_b[c];
        // block max
        float m = lg;
        #pragma unroll
        for (int off = 32; off >= 1; off >>= 1) m = fmaxf(m, __shfl_xor(m, off));
        if (lane == 0) s_red[wid] = m;
        __syncthreads();
        m = fmaxf(fmaxf(s_red[0], s_red[1]), fmaxf(s_red[2], s_red[3]));
        // block sum of exp
        float e = __expf(lg - m);
        float ssum = e;
        #pragma unroll
        for (int off = 32; off >= 1; off >>= 1) ssum += __shfl_xor(ssum, off);
        if (lane == 0) s_red[4 + wid] = ssum;
        __syncthreads();
        ssum = s_red[4] + s_red[5] + s_red[6] + s_red[7];
        s_outT[j][tid] = lg - m - __logf(ssum);
        __syncthreads();
    }
    // transposed write-out: thread tid owns channel row tid, 16 consecutive t
    float* orow = out + ((size_t)b * MU1 + tid) * LL + t0;
    for (int j = 0; j < TT2; j++) orow[j] = s_outT[j][tid];
}

// -------------------------------------------------------------- launch ----
extern "C" void kernel_launch(void* const* d_in, const int* in_sizes, int n_in,
                              void* d_out, int out_size, void* d_ws, size_t ws_size,
                              hipStream_t stream)
{
    const float* lf      = (const float*)d_in[0];
    const int*   gold    = (const int*)  d_in[1];
    const float* embed_W = (const float*)d_in[2];
    const float* embed_b = (const float*)d_in[3];
    const float* up_W    = (const float*)d_in[4];
    const float* up_b    = (const float*)d_in[5];
    const float* cond_W  = (const float*)d_in[6];
    const float* cond_b  = (const float*)d_in[7];
    const float* dil_W   = (const float*)d_in[8];
    const float* dil_b   = (const float*)d_in[9];
    const float* skip_W  = (const float*)d_in[10];
    const float* skip_b  = (const float*)d_in[11];
    const float* res_W   = (const float*)d_in[12];
    const float* res_b   = (const float*)d_in[13];
    const float* W1      = (const float*)d_in[14];
    const float* W2      = (const float*)d_in[15];
    float* out = (float*)d_out;

    float* ws = (float*)d_ws;
    float* sigA     = ws;
    float* sigB     = sigA + (size_t)BB * LL * H;
    float* skip     = sigB + (size_t)BB * LL * H;
    float* condS    = skip + (size_t)BB * LL * SKIPC;
    float* dil_Wt   = condS + (size_t)BB * 256 * NL * H2;
    float* skip_Wt  = dil_Wt + (size_t)NL * 2 * H * H2;
    float* res_Wt   = skip_Wt + (size_t)NL * H * SKIPC;
    float* embed_Wt = res_Wt + (size_t)(NL - 1) * H * H;
    float* cond_Wt  = embed_Wt + (size_t)MU1 * H;
    float* W1t      = cond_Wt + (size_t)LF * NL * H2;
    float* W2t      = W1t + (size_t)MU1 * SKIPC;

    const int prep_n = NL*2*H*H2 + NL*H*SKIPC + (NL-1)*H*H + MU1*H + LF*NL*H2 + MU1*SKIPC + MU1*MU1;
    prep_kernel<<<(prep_n + 255) / 256, 256, 0, stream>>>(
        dil_W, skip_W, res_W, embed_W, cond_W, W1, W2,
        dil_Wt, skip_Wt, res_Wt, embed_Wt, cond_Wt, W1t, W2t);

    embed_kernel<<<(BB * LL * H + 255) / 256, 256, 0, stream>>>(gold, embed_Wt, embed_b, sigA);

    cond_kernel<<<dim3(256, BB), 256, 0, stream>>>(lf, up_W, up_b, cond_Wt, cond_b, condS);

    const int dil[6] = {1, 2, 4, 8, 16, 32};
    float* si = sigA;
    float* so = sigB;
    for (int i = 0; i < NL; i++) {
        int d = dil[i % 6];
        dim3 grid(LL / TT, BB);
        const float* dWt = dil_Wt + (size_t)i * 2 * H * H2;
        const float* dbp = dil_b + i * H2;
        const float* rWt = res_Wt + (size_t)i * H * H;
        const float* rbp = res_b + i * H;
        const float* sWt = skip_Wt + (size_t)i * H * SKIPC;
        const float* sbp = skip_b + i * SKIPC;
        if (i == 0)
            layer_kernel<true, false><<<grid, 256, 0, stream>>>(si, so, skip, dWt, dbp, condS, i * H2, rWt, rbp, sWt, sbp, d);
        else if (i == NL - 1)
            layer_kernel<false, true><<<grid, 256, 0, stream>>>(si, so, skip, dWt, dbp, condS, i * H2, rWt, rbp, sWt, sbp, d);
        else
            layer_kernel<false, false><<<grid, 256, 0, stream>>>(si, so, skip, dWt, dbp, condS, i * H2, rWt, rbp, sWt, sbp, d);
        float* tmp = si; si = so; so = tmp;
    }

    head_kernel<<<dim3(LL / TT2, BB), 256, 0, stream>>>(skip, W1t, W2t, out);
}

// Round 2
// 773.573 us; speedup vs baseline: 3.6403x; 3.6403x over previous
//
#include <hip/hip_runtime.h>
#include <math.h>

#define MU1   256
#define H     64
#define H2    128
#define SKIPC 256
#define NL    24
#define LF    80
#define UPK   4
#define REP   75
#define BB    2
#define LLEN  64
#define LL    19200

using bf16x8 = __attribute__((ext_vector_type(8))) short;
using bf16x4 = __attribute__((ext_vector_type(4))) short;
using f32x4  = __attribute__((ext_vector_type(4))) float;

__device__ __forceinline__ float b2f(short s) {
    union { unsigned u; float f; } v; v.u = ((unsigned)(unsigned short)s) << 16; return v.f;
}
__device__ __forceinline__ short f2b(float f) {
    union { float f; unsigned u; } v; v.f = f;
    unsigned r = (v.u + 0x7fff + ((v.u >> 16) & 1)) >> 16;
    return (short)r;
}

// ---------------------------------------------------------------- prep ----
__global__ __launch_bounds__(256) void prep_kernel(
    const float* __restrict__ dil_W,  const float* __restrict__ skip_W,
    const float* __restrict__ res_W,  const float* __restrict__ embed_W,
    const float* __restrict__ embed_b,const float* __restrict__ cond_W,
    const float* __restrict__ out_W1, const float* __restrict__ out_W2,
    const float* __restrict__ skip_b,
    short* __restrict__ dil_Wb, short* __restrict__ skip_Wb,
    short* __restrict__ res_Wb, short* __restrict__ embed_allb,
    float* __restrict__ cond_Wt, short* __restrict__ W1b,
    short* __restrict__ W2b, float* __restrict__ sbsum)
{
    int idx = blockIdx.x * 256 + threadIdx.x;
    const int n1 = NL * 2 * H2 * H;     // 393216 dil_Wb[i][k][o][c]
    const int n2 = NL * SKIPC * H;      // 393216 skip_Wb[i][s][c]
    const int n3 = (NL - 1) * H * H;    //  94208 res_Wb[i][o][c]
    const int n4 = MU1 * H;             //  16384 embed_allb[g][h]
    const int n5 = LF * NL * H2;        // 245760 cond_Wt[c][o]
    const int n6 = MU1 * SKIPC;         //  65536
    const int n7 = MU1 * MU1;           //  65536
    if (idx < n1) {
        int c = idx & 63; int o = (idx >> 6) & 127;
        int k = (idx >> 13) & 1; int i = idx >> 14;
        dil_Wb[idx] = f2b(dil_W[((i * H2 + o) * H + c) * 2 + k]);
        return;
    }
    idx -= n1;
    if (idx < n2) { skip_Wb[idx] = f2b(skip_W[idx]); return; }
    idx -= n2;
    if (idx < n3) { res_Wb[idx] = f2b(res_W[idx]); return; }
    idx -= n3;
    if (idx < n4) {
        int h = idx & 63; int g = idx >> 6;
        embed_allb[idx] = f2b(embed_W[h * MU1 + g] + embed_b[h]);
        return;
    }
    idx -= n4;
    if (idx < n5) {
        int o = idx % (NL * H2); int c = idx / (NL * H2);
        cond_Wt[idx] = cond_W[o * LF + c];
        return;
    }
    idx -= n5;
    if (idx < n6) { W1b[idx] = f2b(out_W1[idx]); return; }
    idx -= n6;
    if (idx < n7) { W2b[idx] = f2b(out_W2[idx]); return; }
    idx -= n7;
    if (idx < SKIPC) {
        float a = 0.f;
        for (int i = 0; i < NL; i++) a += skip_b[i * SKIPC + idx];
        sbsum[idx] = a;
        return;
    }
}

// --------------------------------------------------------------- embed ----
__global__ __launch_bounds__(256) void embed_kernel(
    const int* __restrict__ gold, const short* __restrict__ eW,
    short* __restrict__ sig)
{
    int idx = blockIdx.x * 256 + threadIdx.x;   // B*LL*8 tasks of 16B
    if (idx >= BB * LL * 8) return;
    int ch = idx & 7; int bt = idx >> 3;
    int g = gold[bt];
    *(bf16x8*)(sig + (size_t)bt * H + ch * 8) = *(const bf16x8*)(eW + g * H + ch * 8);
}

// ---------------------------------------------------------------- cond ----
__global__ __launch_bounds__(256) void cond_kernel(
    const float* __restrict__ lf, const float* __restrict__ up_W,
    const float* __restrict__ up_b, const float* __restrict__ cond_Wt,
    const float* __restrict__ cond_b, const float* __restrict__ dil_b,
    float* __restrict__ condS)
{
    __shared__ float s_up[LF];
    int b = blockIdx.y;
    int j = blockIdx.x;            // 0..255
    int frame = j >> 2, k = j & 3;
    int tid = threadIdx.x;
    if (tid < LF) {
        float acc = up_b[tid];
        const float* lfrow = lf + (b * LLEN + frame) * LF;
        for (int ci = 0; ci < LF; ci++)
            acc += lfrow[ci] * up_W[(ci * LF + tid) * UPK + k];
        s_up[tid] = acc;
    }
    __syncthreads();
    float* dst = condS + ((size_t)(b * 256 + j)) * (NL * H2);
    for (int r = 0; r < (NL * H2) / 256; r++) {
        int o = r * 256 + tid;
        float acc = cond_b[o] + dil_b[o];
        for (int c = 0; c < LF; c++)
            acc += cond_Wt[c * (NL * H2) + o] * s_up[c];
        dst[o] = acc;
    }
}

// --------------------------------------------------------------- layer ----
template<bool LAST>
__global__ __launch_bounds__(256) void layer_mfma(
    const short* __restrict__ sig_in, short* __restrict__ sig_out,
    short* __restrict__ z_grp,         // [B][LL][512], slot il
    const short* __restrict__ dWb,     // [2][128][64] bf16
    const float* __restrict__ condS,   // [B][256][3072]
    int ilayer, int il,
    const short* __restrict__ rWb,     // [64][64]
    const float* __restrict__ rb,
    int d)
{
    __shared__ __align__(16) short s_sig[96][72];
    __shared__ __align__(16) short s_z[64][72];
    __shared__ __align__(16) short s_out[64][72];
    __shared__ float s_cond[2][128];

    const int b = blockIdx.y;
    const int t0 = blockIdx.x * 64;
    const int tid = threadIdx.x;
    const int w = tid >> 6;
    const int lane = tid & 63;
    const int lr = lane & 15, lg = lane >> 4;

    // stage rows t0-32 .. t0+63
    const short* base = sig_in + ((size_t)b * LL + t0 - 32) * H;
    #pragma unroll
    for (int it = 0; it < 3; ++it) {
        int task = tid + it * 256;       // 768 = 96 rows x 8 chunks
        int r = task >> 3, ch = task & 7;
        bf16x8 v = {};
        if (t0 - 32 + r >= 0) v = *(const bf16x8*)(base + r * H + ch * 8);
        *(bf16x8*)&s_sig[r][ch * 8] = v;
    }
    {
        int col0 = t0 / REP;
        int col1 = (t0 + 63) / REP;
        int sel = tid >> 7, o = tid & 127;
        int col = sel ? col1 : col0;
        s_cond[sel][o] = condS[((size_t)(b * 256 + col)) * (NL * H2) + ilayer * H2 + o];
    }
    __syncthreads();

    // gated GEMM: M=16/wave, N=128, K=128 (prev 64 | cur 64)
    f32x4 acc[8];
    #pragma unroll
    for (int nt = 0; nt < 8; ++nt) acc[nt] = (f32x4){0.f, 0.f, 0.f, 0.f};
    bf16x8 af[4];
    #pragma unroll
    for (int kk = 0; kk < 4; ++kk) {
        int rowb = (kk < 2 ? 32 - d : 32) + 16 * w + lr;
        int colb = (kk & 1) * 32 + 8 * lg;
        af[kk] = *(const bf16x8*)&s_sig[rowb][colb];
    }
    #pragma unroll
    for (int nt = 0; nt < 8; ++nt) {
        #pragma unroll
        for (int kk = 0; kk < 4; ++kk) {
            const short* bp = dWb + (((kk >> 1) * H2 + 16 * nt + lr) * H) + (kk & 1) * 32 + 8 * lg;
            bf16x8 bw = *(const bf16x8*)bp;
            acc[nt] = __builtin_amdgcn_mfma_f32_16x16x32_bf16(af[kk], bw, acc[nt], 0, 0, 0);
        }
    }
    // gate epilogue -> s_z
    {
        int bnd = (t0 / REP + 1) * REP - t0;
        #pragma unroll
        for (int nt = 0; nt < 4; ++nt) {
            #pragma unroll
            for (int reg = 0; reg < 4; ++reg) {
                int tl = 16 * w + 4 * lg + reg;
                int sel = (tl >= bnd) ? 1 : 0;
                int o = 16 * nt + lr;
                float afv = acc[nt][reg] + s_cond[sel][o];
                float agv = acc[nt + 4][reg] + s_cond[sel][64 + o];
                float ef = __expf(2.f * afv);
                float th = 1.f - 2.f / (ef + 1.f);
                float sg = 1.f / (1.f + __expf(-agv));
                s_z[tl][o] = f2b(th * sg);
            }
        }
    }
    __syncthreads();

    // residual GEMM: sig_out = sig + z @ rW + rb
    if (!LAST) {
        f32x4 racc[4];
        #pragma unroll
        for (int nt = 0; nt < 4; ++nt) racc[nt] = (f32x4){0.f, 0.f, 0.f, 0.f};
        bf16x8 za[2];
        #pragma unroll
        for (int kk = 0; kk < 2; ++kk)
            za[kk] = *(const bf16x8*)&s_z[16 * w + lr][32 * kk + 8 * lg];
        #pragma unroll
        for (int nt = 0; nt < 4; ++nt) {
            #pragma unroll
            for (int kk = 0; kk < 2; ++kk) {
                const short* bp = rWb + (16 * nt + lr) * H + 32 * kk + 8 * lg;
                bf16x8 bw = *(const bf16x8*)bp;
                racc[nt] = __builtin_amdgcn_mfma_f32_16x16x32_bf16(za[kk], bw, racc[nt], 0, 0, 0);
            }
        }
        #pragma unroll
        for (int nt = 0; nt < 4; ++nt) {
            float rbv = rb[16 * nt + lr];
            #pragma unroll
            for (int reg = 0; reg < 4; ++reg) {
                int tl = 16 * w + 4 * lg + reg;
                int c = 16 * nt + lr;
                float v = b2f(s_sig[32 + tl][c]) + racc[nt][reg] + rbv;
                s_out[tl][c] = f2b(v);
            }
        }
    }
    __syncthreads();

    // global writes (coalesced via LDS)
    #pragma unroll
    for (int it = 0; it < 2; ++it) {
        int task = tid + it * 256;       // 512 = 64 rows x 8 chunks
        int r = task >> 3, ch = task & 7;
        *(bf16x8*)(z_grp + ((size_t)(b * LL + t0 + r)) * 512 + il * H + ch * 8)
            = *(const bf16x8*)&s_z[r][ch * 8];
        if (!LAST)
            *(bf16x8*)(sig_out + ((size_t)(b * LL + t0 + r)) * H + ch * 8)
                = *(const bf16x8*)&s_out[r][ch * 8];
    }
}

// ----------------------------------------------------------- skip GEMM ----
// skipS[b][t][s] (+)= z_grp[b][t][0:512] @ sWb[0:8 layers][s][0:64]
template<bool G0>
__global__ __launch_bounds__(256) void skip_gemm(
    const short* __restrict__ z_grp, const short* __restrict__ sWb,
    float* __restrict__ skipS)
{
    __shared__ __align__(16) short s_a[64][136];
    const int b = blockIdx.y;
    const int t0 = blockIdx.x * 64;
    const int tid = threadIdx.x;
    const int w = tid >> 6;
    const int lane = tid & 63;
    const int lr = lane & 15, lg = lane >> 4;

    f32x4 acc[4][4];
    #pragma unroll
    for (int mt = 0; mt < 4; ++mt)
        #pragma unroll
        for (int nt = 0; nt < 4; ++nt) acc[mt][nt] = (f32x4){0.f, 0.f, 0.f, 0.f};

    for (int chunk = 0; chunk < 4; ++chunk) {
        __syncthreads();
        #pragma unroll
        for (int it = 0; it < 4; ++it) {
            int task = tid + it * 256;   // 1024 = 64 rows x 16 chunks
            int r = task >> 4, ch = task & 15;
            *(bf16x8*)&s_a[r][ch * 8] =
                *(const bf16x8*)(z_grp + ((size_t)(b * LL + t0 + r)) * 512 + chunk * 128 + ch * 8);
        }
        __syncthreads();
        bf16x8 bw[4][4];
        #pragma unroll
        for (int nt = 0; nt < 4; ++nt)
            #pragma unroll
            for (int kk = 0; kk < 4; ++kk) {
                int layer = 2 * chunk + (kk >> 1);
                bw[nt][kk] = *(const bf16x8*)(sWb +
                    ((size_t)(layer * SKIPC + 64 * w + 16 * nt + lr)) * H + (kk & 1) * 32 + 8 * lg);
            }
        #pragma unroll
        for (int mt = 0; mt < 4; ++mt) {
            bf16x8 afr[4];
            #pragma unroll
            for (int kk = 0; kk < 4; ++kk)
                afr[kk] = *(const bf16x8*)&s_a[16 * mt + lr][32 * kk + 8 * lg];
            #pragma unroll
            for (int nt = 0; nt < 4; ++nt)
                #pragma unroll
                for (int kk = 0; kk < 4; ++kk)
                    acc[mt][nt] = __builtin_amdgcn_mfma_f32_16x16x32_bf16(afr[kk], bw[nt][kk], acc[mt][nt], 0, 0, 0);
        }
    }
    #pragma unroll
    for (int mt = 0; mt < 4; ++mt)
        #pragma unroll
        for (int nt = 0; nt < 4; ++nt) {
            int s = 64 * w + 16 * nt + lr;
            #pragma unroll
            for (int reg = 0; reg < 4; ++reg) {
                int t = t0 + 16 * mt + 4 * lg + reg;
                float* p = skipS + ((size_t)(b * LL + t)) * SKIPC + s;
                float v = acc[mt][nt][reg];
                if (!G0) v += *p;
                *p = v;
            }
        }
}

// ---------------------------------------------------------------- head ----
__global__ __launch_bounds__(256) void head_mfma(
    const float* __restrict__ skipS, const float* __restrict__ sbsum,
    const short* __restrict__ W1b, const short* __restrict__ W2b,
    float* __restrict__ out)
{
    __shared__ __align__(16) unsigned char smem[128 * 68 * 4];  // 34816 B
    short (*s_x)[264] = (short(*)[264])smem;                    // 64x264 bf16 = 33792 B
    float (*s_o)[68]  = (float(*)[68])smem;                     // 128x68 f32
    __shared__ float s_red[4][64];
    __shared__ float s_sb[256];

    const int b = blockIdx.y;
    const int t0 = blockIdx.x * 64;
    const int tid = threadIdx.x;
    const int w = tid >> 6;
    const int lane = tid & 63;
    const int lr = lane & 15, lg = lane >> 4;

    s_sb[tid] = sbsum[tid];
    __syncthreads();

    // stage x = bf16(relu(skip + sb))
    #pragma unroll
    for (int it = 0; it < 16; ++it) {
        int task = tid + it * 256;     // 4096 = 64 rows x 64 float4
        int r = task >> 6, c4 = task & 63;
        f32x4 v = *(const f32x4*)(skipS + ((size_t)(b * LL + t0 + r)) * SKIPC + c4 * 4);
        bf16x4 o;
        #pragma unroll
        for (int j = 0; j < 4; ++j) o[j] = f2b(fmaxf(v[j] + s_sb[c4 * 4 + j], 0.f));
        *(bf16x4*)&s_x[r][c4 * 4] = o;
    }
    __syncthreads();

    // GEMM1: h = relu(x @ W1^T), N-slice 64/wave
    f32x4 acc1[4][4];
    #pragma unroll
    for (int mt = 0; mt < 4; ++mt)
        #pragma unroll
        for (int nt = 0; nt < 4; ++nt) acc1[mt][nt] = (f32x4){0.f, 0.f, 0.f, 0.f};
    #pragma unroll
    for (int mt = 0; mt < 4; ++mt) {
        bf16x8 afr[8];
        #pragma unroll
        for (int kk = 0; kk < 8; ++kk)
            afr[kk] = *(const bf16x8*)&s_x[16 * mt + lr][32 * kk + 8 * lg];
        #pragma unroll
        for (int nt = 0; nt < 4; ++nt)
            #pragma unroll
            for (int kk = 0; kk < 8; ++kk) {
                bf16x8 bw = *(const bf16x8*)(W1b + ((size_t)(64 * w + 16 * nt + lr)) * MU1 + 32 * kk + 8 * lg);
                acc1[mt][nt] = __builtin_amdgcn_mfma_f32_16x16x32_bf16(afr[kk], bw, acc1[mt][nt], 0, 0, 0);
            }
    }
    __syncthreads();
    #pragma unroll
    for (int mt = 0; mt < 4; ++mt)
        #pragma unroll
        for (int nt = 0; nt < 4; ++nt)
            #pragma unroll
            for (int reg = 0; reg < 4; ++reg) {
                int tl = 16 * mt + 4 * lg + reg;
                int o = 64 * w + 16 * nt + lr;
                s_x[tl][o] = f2b(fmaxf(acc1[mt][nt][reg], 0.f));
            }
    __syncthreads();

    // GEMM2: logits
    f32x4 acc2[4][4];
    #pragma unroll
    for (int mt = 0; mt < 4; ++mt)
        #pragma unroll
        for (int nt = 0; nt < 4; ++nt) acc2[mt][nt] = (f32x4){0.f, 0.f, 0.f, 0.f};
    #pragma unroll
    for (int mt = 0; mt < 4; ++mt) {
        bf16x8 afr[8];
        #pragma unroll
        for (int kk = 0; kk < 8; ++kk)
            afr[kk] = *(const bf16x8*)&s_x[16 * mt + lr][32 * kk + 8 * lg];
        #pragma unroll
        for (int nt = 0; nt < 4; ++nt)
            #pragma unroll
            for (int kk = 0; kk < 8; ++kk) {
                bf16x8 bw = *(const bf16x8*)(W2b + ((size_t)(64 * w + 16 * nt + lr)) * MU1 + 32 * kk + 8 * lg);
                acc2[mt][nt] = __builtin_amdgcn_mfma_f32_16x16x32_bf16(afr[kk], bw, acc2[mt][nt], 0, 0, 0);
            }
    }

    // log-softmax over 256 channels (4 waves x 64 ch)
    float mv[4][4];
    #pragma unroll
    for (int mt = 0; mt < 4; ++mt)
        #pragma unroll
        for (int reg = 0; reg < 4; ++reg) {
            float m = -3.4e38f;
            #pragma unroll
            for (int nt = 0; nt < 4; ++nt) m = fmaxf(m, acc2[mt][nt][reg]);
            #pragma unroll
            for (int off = 1; off <= 8; off <<= 1) m = fmaxf(m, __shfl_xor(m, off));
            int tl = 16 * mt + 4 * lg + reg;
            if (lr == 0) s_red[w][tl] = m;
        }
    __syncthreads();
    #pragma unroll
    for (int mt = 0; mt < 4; ++mt)
        #pragma unroll
        for (int reg = 0; reg < 4; ++reg) {
            int tl = 16 * mt + 4 * lg + reg;
            mv[mt][reg] = fmaxf(fmaxf(s_red[0][tl], s_red[1][tl]), fmaxf(s_red[2][tl], s_red[3][tl]));
        }
    __syncthreads();
    #pragma unroll
    for (int mt = 0; mt < 4; ++mt)
        #pragma unroll
        for (int reg = 0; reg < 4; ++reg) {
            float s = 0.f;
            #pragma unroll
            for (int nt = 0; nt < 4; ++nt) s += __expf(acc2[mt][nt][reg] - mv[mt][reg]);
            #pragma unroll
            for (int off = 1; off <= 8; off <<= 1) s += __shfl_xor(s, off);
            int tl = 16 * mt + 4 * lg + reg;
            if (lr == 0) s_red[w][tl] = s;
        }
    __syncthreads();
    #pragma unroll
    for (int mt = 0; mt < 4; ++mt)
        #pragma unroll
        for (int reg = 0; reg < 4; ++reg) {
            int tl = 16 * mt + 4 * lg + reg;
            float denom = s_red[0][tl] + s_red[1][tl] + s_red[2][tl] + s_red[3][tl];
            mv[mt][reg] = mv[mt][reg] + logf(denom);   // lse
        }
    __syncthreads();   // done with s_x/s_red reads; reuse smem as s_o

    // two transpose passes: channels [0,128) then [128,256)
    #pragma unroll
    for (int pass = 0; pass < 2; ++pass) {
        if ((w >> 1) == pass) {
            #pragma unroll
            for (int mt = 0; mt < 4; ++mt)
                #pragma unroll
                for (int nt = 0; nt < 4; ++nt)
                    #pragma unroll
                    for (int reg = 0; reg < 4; ++reg) {
                        int ch = 64 * (w & 1) + 16 * nt + lr;
                        int tl = 16 * mt + 4 * lg + reg;
                        s_o[ch][tl] = acc2[mt][nt][reg] - mv[mt][reg];
                    }
        }
        __syncthreads();
        {
            int row = tid >> 1, half = tid & 1;
            float* op = out + ((size_t)(b * MU1 + pass * 128 + row)) * LL + t0 + half * 32;
            #pragma unroll
            for (int k = 0; k < 8; ++k)
                *(f32x4*)(op + 4 * k) = *(const f32x4*)&s_o[row][half * 32 + 4 * k];
        }
        __syncthreads();
    }
}

// -------------------------------------------------------------- launch ----
extern "C" void kernel_launch(void* const* d_in, const int* in_sizes, int n_in,
                              void* d_out, int out_size, void* d_ws, size_t ws_size,
                              hipStream_t stream)
{
    const float* lf      = (const float*)d_in[0];
    const int*   gold    = (const int*)  d_in[1];
    const float* embed_W = (const float*)d_in[2];
    const float* embed_b = (const float*)d_in[3];
    const float* up_W    = (const float*)d_in[4];
    const float* up_b    = (const float*)d_in[5];
    const float* cond_W  = (const float*)d_in[6];
    const float* cond_b  = (const float*)d_in[7];
    const float* dil_W   = (const float*)d_in[8];
    const float* dil_b   = (const float*)d_in[9];
    const float* skip_W  = (const float*)d_in[10];
    const float* skip_b  = (const float*)d_in[11];
    const float* res_W   = (const float*)d_in[12];
    const float* res_b   = (const float*)d_in[13];
    const float* W1      = (const float*)d_in[14];
    const float* W2      = (const float*)d_in[15];
    float* out = (float*)d_out;

    unsigned char* p = (unsigned char*)d_ws;
    short* sigA      = (short*)p; p += (size_t)BB * LL * H * 2;          // 4.9 MB
    short* sigB      = (short*)p; p += (size_t)BB * LL * H * 2;          // 4.9 MB
    short* z_grp     = (short*)p; p += (size_t)BB * LL * 512 * 2;        // 39.3 MB
    float* skipS     = (float*)p; p += (size_t)BB * LL * SKIPC * 4;      // 39.3 MB
    float* condS     = (float*)p; p += (size_t)BB * 256 * NL * H2 * 4;   // 6.3 MB
    short* dil_Wb    = (short*)p; p += (size_t)NL * 2 * H2 * H * 2;
    short* skip_Wb   = (short*)p; p += (size_t)NL * SKIPC * H * 2;
    short* res_Wb    = (short*)p; p += (size_t)(NL - 1) * H * H * 2;
    short* embed_allb= (short*)p; p += (size_t)MU1 * H * 2;
    float* cond_Wt   = (float*)p; p += (size_t)LF * NL * H2 * 4;
    short* W1b       = (short*)p; p += (size_t)MU1 * SKIPC * 2;
    short* W2b       = (short*)p; p += (size_t)MU1 * MU1 * 2;
    float* sbsum     = (float*)p; p += (size_t)SKIPC * 4;

    const int prep_n = NL*2*H2*H + NL*SKIPC*H + (NL-1)*H*H + MU1*H + LF*NL*H2 + MU1*SKIPC + MU1*MU1 + SKIPC;
    prep_kernel<<<(prep_n + 255) / 256, 256, 0, stream>>>(
        dil_W, skip_W, res_W, embed_W, embed_b, cond_W, W1, W2, skip_b,
        dil_Wb, skip_Wb, res_Wb, embed_allb, cond_Wt, W1b, W2b, sbsum);

    embed_kernel<<<(BB * LL * 8 + 255) / 256, 256, 0, stream>>>(gold, embed_allb, sigA);

    cond_kernel<<<dim3(256, BB), 256, 0, stream>>>(lf, up_W, up_b, cond_Wt, cond_b, dil_b, condS);

    const int dil[6] = {1, 2, 4, 8, 16, 32};
    short* si = sigA;
    short* so = sigB;
    dim3 grid(LL / 64, BB);
    for (int i = 0; i < NL; i++) {
        int d = dil[i % 6];
        const short* dWb = dil_Wb + (size_t)i * 2 * H2 * H;
        const short* rWb = (i < NL - 1) ? res_Wb + (size_t)i * H * H : res_Wb;
        const float* rbp = (i < NL - 1) ? res_b + i * H : res_b;
        if (i == NL - 1)
            layer_mfma<true><<<grid, 256, 0, stream>>>(si, so, z_grp, dWb, condS, i, i & 7, rWb, rbp, d);
        else
            layer_mfma<false><<<grid, 256, 0, stream>>>(si, so, z_grp, dWb, condS, i, i & 7, rWb, rbp, d);
        short* tmp = si; si = so; so = tmp;

        if ((i & 7) == 7) {
            int g = i >> 3;
            const short* sWb = skip_Wb + (size_t)g * 8 * SKIPC * H;
            if (g == 0)
                skip_gemm<true><<<grid, 256, 0, stream>>>(z_grp, sWb, skipS);
            else
                skip_gemm<false><<<grid, 256, 0, stream>>>(z_grp, sWb, skipS);
        }
    }

    head_mfma<<<grid, 256, 0, stream>>>(skipS, sbsum, W1b, W2b, out);
}

// Round 3
// 577.432 us; speedup vs baseline: 4.8768x; 1.3397x over previous
//
#include <hip/hip_runtime.h>
#include <math.h>

#define MU1   256
#define H     64
#define H2    128
#define SKIPC 256
#define NL    24
#define LF    80
#define UPK   4
#define REP   75
#define BB    2
#define LLEN  64
#define LL    19200

using bf16x8 = __attribute__((ext_vector_type(8))) short;
using bf16x4 = __attribute__((ext_vector_type(4))) short;
using f32x4  = __attribute__((ext_vector_type(4))) float;

__device__ __forceinline__ float b2f(short s) {
    union { unsigned u; float f; } v; v.u = ((unsigned)(unsigned short)s) << 16; return v.f;
}
__device__ __forceinline__ short f2b(float f) {
    union { float f; unsigned u; } v; v.f = f;
    unsigned r = (v.u + 0x7fff + ((v.u >> 16) & 1)) >> 16;
    return (short)r;
}

// ---------------------------------------------------------------- prep ----
__global__ __launch_bounds__(256) void prep_kernel(
    const float* __restrict__ dil_W,  const float* __restrict__ skip_W,
    const float* __restrict__ res_W,  const float* __restrict__ embed_W,
    const float* __restrict__ embed_b,const float* __restrict__ cond_W,
    const float* __restrict__ out_W1, const float* __restrict__ out_W2,
    const float* __restrict__ skip_b,
    short* __restrict__ dil_Wb, short* __restrict__ skip_Wb,
    short* __restrict__ res_Wb, short* __restrict__ embed_allb,
    float* __restrict__ cond_Wt, short* __restrict__ W1b,
    short* __restrict__ W2b, float* __restrict__ sbsum)
{
    int idx = blockIdx.x * 256 + threadIdx.x;
    const int n1 = NL * 2 * H2 * H;     // dil_Wb[i][k][o][c]
    const int n2 = NL * SKIPC * H;      // skip_Wb[i][s][c]
    const int n3 = (NL - 1) * H * H;    // res_Wb[i][o][c]
    const int n4 = MU1 * H;             // embed_allb[g][h]
    const int n5 = LF * NL * H2;        // cond_Wt[c][o]
    const int n6 = MU1 * SKIPC;
    const int n7 = MU1 * MU1;
    if (idx < n1) {
        int c = idx & 63; int o = (idx >> 6) & 127;
        int k = (idx >> 13) & 1; int i = idx >> 14;
        dil_Wb[idx] = f2b(dil_W[((i * H2 + o) * H + c) * 2 + k]);
        return;
    }
    idx -= n1;
    if (idx < n2) { skip_Wb[idx] = f2b(skip_W[idx]); return; }
    idx -= n2;
    if (idx < n3) { res_Wb[idx] = f2b(res_W[idx]); return; }
    idx -= n3;
    if (idx < n4) {
        int h = idx & 63; int g = idx >> 6;
        embed_allb[idx] = f2b(embed_W[h * MU1 + g] + embed_b[h]);
        return;
    }
    idx -= n4;
    if (idx < n5) {
        int o = idx % (NL * H2); int c = idx / (NL * H2);
        cond_Wt[idx] = cond_W[o * LF + c];
        return;
    }
    idx -= n5;
    if (idx < n6) { W1b[idx] = f2b(out_W1[idx]); return; }
    idx -= n6;
    if (idx < n7) { W2b[idx] = f2b(out_W2[idx]); return; }
    idx -= n7;
    if (idx < SKIPC) {
        float a = 0.f;
        for (int i = 0; i < NL; i++) a += skip_b[i * SKIPC + idx];
        sbsum[idx] = a;
        return;
    }
}

// --------------------------------------------------------------- embed ----
__global__ __launch_bounds__(256) void embed_kernel(
    const int* __restrict__ gold, const short* __restrict__ eW,
    short* __restrict__ sig)
{
    int idx = blockIdx.x * 256 + threadIdx.x;
    if (idx >= BB * LL * 8) return;
    int ch = idx & 7; int bt = idx >> 3;
    int g = gold[bt];
    *(bf16x8*)(sig + (size_t)bt * H + ch * 8) = *(const bf16x8*)(eW + g * H + ch * 8);
}

// ---------------------------------------------------------------- cond ----
// grid (256 j, 12 o-tiles, B): one output per thread, K=80 from LDS.
__global__ __launch_bounds__(256) void cond_kernel(
    const float* __restrict__ lf, const float* __restrict__ up_W,
    const float* __restrict__ up_b, const float* __restrict__ cond_Wt,
    const float* __restrict__ cond_b, const float* __restrict__ dil_b,
    float* __restrict__ condS)
{
    __shared__ float s_up[LF];
    int j = blockIdx.x;
    int ot = blockIdx.y;
    int b = blockIdx.z;
    int frame = j >> 2, k = j & 3;
    int tid = threadIdx.x;
    if (tid < LF) {
        float a = up_b[tid];
        const float* lfr = lf + (b * LLEN + frame) * LF;
        #pragma unroll 8
        for (int c = 0; c < LF; ++c) a += lfr[c] * up_W[(c * LF + tid) * UPK + k];
        s_up[tid] = a;
    }
    __syncthreads();
    int o = ot * 256 + tid;
    float a = cond_b[o] + dil_b[o];
    #pragma unroll 8
    for (int c = 0; c < LF; ++c) a += cond_Wt[c * 3072 + o] * s_up[c];
    condS[((size_t)(b * 256 + j)) * 3072 + o] = a;
}

// ---------------------------------------------------- fused layer pair ----
// Layers iA=2p (dilation dA in {1,4,16}) and iB=2p+1 (dB in {2,8,32}).
// TT=96 output rows; A computes 128 rows [t0-32,t0+96) (halo dB<=32),
// B computes 96 rows. All intermediate state in LDS.
template<bool LASTPAIR>
__global__ __launch_bounds__(256) void pair_mfma(
    const short* __restrict__ sig_in, short* __restrict__ sig_out,
    short* __restrict__ z_grp,
    const short* __restrict__ dil_Wb_all,
    const short* __restrict__ res_Wb_all,
    const float* __restrict__ res_b_all,
    const float* __restrict__ condS,
    int p, int dA, int dB)
{
    __shared__ __align__(16) short sa[144][72];   // input rows [t0-48, t0+96)
    __shared__ __align__(16) short sb[128][72];   // A output rows [t0-32, t0+96)
    __shared__ __align__(16) short sz[128][72];   // z scratch
    __shared__ float scond[2][3][128];

    const int iA = 2 * p, iB = 2 * p + 1;
    const int b = blockIdx.y;
    const int t0 = blockIdx.x * 96;
    const int tid = threadIdx.x;
    const int w = tid >> 6;
    const int lane = tid & 63;
    const int lr = lane & 15, lg = lane >> 4;
    const int c0 = (t0 >= 32) ? (t0 - 32) / 75 : 0;

    // ---- stage input + cond ----
    {
        const short* basein = sig_in + (size_t)b * LL * H;
        #pragma unroll
        for (int it = 0; it < 5; ++it) {
            int task = tid + it * 256;
            if (task < 1152) {
                int r = task >> 3, ch = task & 7;
                int t = t0 - 48 + r;
                bf16x8 v = {};
                if (t >= 0) v = *(const bf16x8*)(basein + (size_t)t * H + ch * 8);
                *(bf16x8*)&sa[r][ch * 8] = v;
            }
        }
        #pragma unroll
        for (int it = 0; it < 3; ++it) {
            int task = tid + it * 256;      // 768 = 2 sel x 3 col x 128
            int sel = task >= 384;
            int cj = (task - sel * 384) >> 7;
            int o = task & 127;
            int col = c0 + cj; col = col > 255 ? 255 : col;
            scond[sel][cj][o] = condS[((size_t)(b * 256 + col)) * 3072 + (iA + sel) * 128 + o];
        }
    }
    __syncthreads();

    // ---- A gated GEMM: M=128 (2 Mtiles/wave), N=128, K=128 ----
    {
        const short* dW = dil_Wb_all + (size_t)iA * 2 * H2 * H;
        f32x4 acc[2][8];
        #pragma unroll
        for (int m = 0; m < 2; ++m)
            #pragma unroll
            for (int n = 0; n < 8; ++n) acc[m][n] = (f32x4){0.f, 0.f, 0.f, 0.f};
        bf16x8 afA[2][4];
        #pragma unroll
        for (int m = 0; m < 2; ++m) {
            int rc = 16 + 16 * (2 * w + m) + lr;
            afA[m][0] = *(const bf16x8*)&sa[rc - dA][lg * 8];
            afA[m][1] = *(const bf16x8*)&sa[rc - dA][32 + lg * 8];
            afA[m][2] = *(const bf16x8*)&sa[rc][lg * 8];
            afA[m][3] = *(const bf16x8*)&sa[rc][32 + lg * 8];
        }
        #pragma unroll
        for (int n = 0; n < 8; ++n)
            #pragma unroll
            for (int kk = 0; kk < 4; ++kk) {
                bf16x8 bw = *(const bf16x8*)(dW + (((kk >> 1) * H2 + 16 * n + lr) * H) + (kk & 1) * 32 + lg * 8);
                acc[0][n] = __builtin_amdgcn_mfma_f32_16x16x32_bf16(afA[0][kk], bw, acc[0][n], 0, 0, 0);
                acc[1][n] = __builtin_amdgcn_mfma_f32_16x16x32_bf16(afA[1][kk], bw, acc[1][n], 0, 0, 0);
            }
        #pragma unroll
        for (int m = 0; m < 2; ++m)
            #pragma unroll
            for (int n = 0; n < 4; ++n)
                #pragma unroll
                for (int r = 0; r < 4; ++r) {
                    int relt = -32 + 16 * (2 * w + m) + 4 * lg + r;
                    int t = t0 + relt;
                    int o = 16 * n + lr;
                    short zb = 0;
                    if (t >= 0) {
                        int ci = t / 75 - c0;
                        float av = acc[m][n][r] + scond[0][ci][o];
                        float gv = acc[m][n + 4][r] + scond[0][ci][64 + o];
                        float th = 1.f - 2.f / (__expf(2.f * av) + 1.f);
                        float sg = 1.f / (1.f + __expf(-gv));
                        zb = f2b(th * sg);
                    }
                    sz[relt + 32][o] = zb;
                }
    }
    __syncthreads();

    // z_A -> global (rows [0,96))
    #pragma unroll
    for (int it = 0; it < 3; ++it) {
        int task = tid + it * 256;
        int r = task >> 3, ch = task & 7;
        *(bf16x8*)(z_grp + ((size_t)(b * LL + t0 + r)) * 512 + (iA & 7) * 64 + ch * 8)
            = *(const bf16x8*)&sz[32 + r][ch * 8];
    }

    // ---- A residual: sb = sa + z @ rW + rb ----
    {
        const short* rW = res_Wb_all + (size_t)iA * H * H;
        const float* rb_ = res_b_all + (size_t)iA * H;
        f32x4 rac[2][4];
        #pragma unroll
        for (int m = 0; m < 2; ++m)
            #pragma unroll
            for (int n = 0; n < 4; ++n) rac[m][n] = (f32x4){0.f, 0.f, 0.f, 0.f};
        bf16x8 za[2][2];
        #pragma unroll
        for (int m = 0; m < 2; ++m) {
            int row = 16 * (2 * w + m) + lr;
            za[m][0] = *(const bf16x8*)&sz[row][lg * 8];
            za[m][1] = *(const bf16x8*)&sz[row][32 + lg * 8];
        }
        #pragma unroll
        for (int n = 0; n < 4; ++n)
            #pragma unroll
            for (int kk = 0; kk < 2; ++kk) {
                bf16x8 bw = *(const bf16x8*)(rW + (16 * n + lr) * H + kk * 32 + lg * 8);
                rac[0][n] = __builtin_amdgcn_mfma_f32_16x16x32_bf16(za[0][kk], bw, rac[0][n], 0, 0, 0);
                rac[1][n] = __builtin_amdgcn_mfma_f32_16x16x32_bf16(za[1][kk], bw, rac[1][n], 0, 0, 0);
            }
        #pragma unroll
        for (int n = 0; n < 4; ++n) {
            float rbv = rb_[16 * n + lr];
            #pragma unroll
            for (int m = 0; m < 2; ++m)
                #pragma unroll
                for (int r = 0; r < 4; ++r) {
                    int relt = -32 + 16 * (2 * w + m) + 4 * lg + r;
                    int t = t0 + relt;
                    int c = 16 * n + lr;
                    short vb = 0;
                    if (t >= 0) vb = f2b(b2f(sa[relt + 48][c]) + rac[m][n][r] + rbv);
                    sb[relt + 32][c] = vb;
                }
        }
    }
    __syncthreads();

    // ---- B gated GEMM: M=96 (6 Mtiles), N-split: wave w -> Ntiles (w, w+4) ----
    {
        const short* dW = dil_Wb_all + (size_t)iB * 2 * H2 * H;
        f32x4 accF[6], accG[6];
        #pragma unroll
        for (int m = 0; m < 6; ++m) { accF[m] = (f32x4){0.f,0.f,0.f,0.f}; accG[m] = (f32x4){0.f,0.f,0.f,0.f}; }
        bf16x8 bwF[4], bwG[4];
        #pragma unroll
        for (int kk = 0; kk < 4; ++kk) {
            int oF = 16 * w + lr;
            bwF[kk] = *(const bf16x8*)(dW + (((kk >> 1) * H2 + oF) * H) + (kk & 1) * 32 + lg * 8);
            bwG[kk] = *(const bf16x8*)(dW + (((kk >> 1) * H2 + 64 + oF) * H) + (kk & 1) * 32 + lg * 8);
        }
        #pragma unroll
        for (int m = 0; m < 6; ++m) {
            int rc = 32 + 16 * m + lr;
            bf16x8 af[4];
            af[0] = *(const bf16x8*)&sb[rc - dB][lg * 8];
            af[1] = *(const bf16x8*)&sb[rc - dB][32 + lg * 8];
            af[2] = *(const bf16x8*)&sb[rc][lg * 8];
            af[3] = *(const bf16x8*)&sb[rc][32 + lg * 8];
            #pragma unroll
            for (int kk = 0; kk < 4; ++kk)
                accF[m] = __builtin_amdgcn_mfma_f32_16x16x32_bf16(af[kk], bwF[kk], accF[m], 0, 0, 0);
            #pragma unroll
            for (int kk = 0; kk < 4; ++kk)
                accG[m] = __builtin_amdgcn_mfma_f32_16x16x32_bf16(af[kk], bwG[kk], accG[m], 0, 0, 0);
        }
        #pragma unroll
        for (int m = 0; m < 6; ++m)
            #pragma unroll
            for (int r = 0; r < 4; ++r) {
                int relt = 16 * m + 4 * lg + r;
                int t = t0 + relt;
                int o = 16 * w + lr;
                int ci = t / 75 - c0;
                float av = accF[m][r] + scond[1][ci][o];
                float gv = accG[m][r] + scond[1][ci][64 + o];
                float th = 1.f - 2.f / (__expf(2.f * av) + 1.f);
                float sg = 1.f / (1.f + __expf(-gv));
                sz[relt][o] = f2b(th * sg);
            }
    }
    __syncthreads();

    // z_B -> global (rows [0,96))
    #pragma unroll
    for (int it = 0; it < 3; ++it) {
        int task = tid + it * 256;
        int r = task >> 3, ch = task & 7;
        *(bf16x8*)(z_grp + ((size_t)(b * LL + t0 + r)) * 512 + (iB & 7) * 64 + ch * 8)
            = *(const bf16x8*)&sz[r][ch * 8];
    }

    // ---- B residual -> sig_out (rows [0,96)), N-split: wave w -> Ntile w ----
    if (!LASTPAIR) {
        const short* rW = res_Wb_all + (size_t)iB * H * H;
        const float* rb_ = res_b_all + (size_t)iB * H;
        int c = 16 * w + lr;
        f32x4 rac[6];
        #pragma unroll
        for (int m = 0; m < 6; ++m) rac[m] = (f32x4){0.f, 0.f, 0.f, 0.f};
        bf16x8 bwR[2];
        bwR[0] = *(const bf16x8*)(rW + c * H + lg * 8);
        bwR[1] = *(const bf16x8*)(rW + c * H + 32 + lg * 8);
        #pragma unroll
        for (int m = 0; m < 6; ++m) {
            bf16x8 z0 = *(const bf16x8*)&sz[16 * m + lr][lg * 8];
            bf16x8 z1 = *(const bf16x8*)&sz[16 * m + lr][32 + lg * 8];
            rac[m] = __builtin_amdgcn_mfma_f32_16x16x32_bf16(z0, bwR[0], rac[m], 0, 0, 0);
            rac[m] = __builtin_amdgcn_mfma_f32_16x16x32_bf16(z1, bwR[1], rac[m], 0, 0, 0);
        }
        float rbv = rb_[c];
        #pragma unroll
        for (int m = 0; m < 6; ++m)
            #pragma unroll
            for (int r = 0; r < 4; ++r) {
                int relt = 16 * m + 4 * lg + r;
                sa[relt][c] = f2b(b2f(sb[relt + 32][c]) + rac[m][r] + rbv);
            }
        __syncthreads();
        #pragma unroll
        for (int it = 0; it < 3; ++it) {
            int task = tid + it * 256;
            int r = task >> 3, ch = task & 7;
            *(bf16x8*)(sig_out + ((size_t)(b * LL + t0 + r)) * H + ch * 8)
                = *(const bf16x8*)&sa[r][ch * 8];
        }
    }
}

// ----------------------------------------------------------- skip GEMM ----
template<bool G0>
__global__ __launch_bounds__(256) void skip_gemm(
    const short* __restrict__ z_grp, const short* __restrict__ sWb,
    float* __restrict__ skipS)
{
    __shared__ __align__(16) short s_a[64][136];
    const int b = blockIdx.y;
    const int t0 = blockIdx.x * 64;
    const int tid = threadIdx.x;
    const int w = tid >> 6;
    const int lane = tid & 63;
    const int lr = lane & 15, lg = lane >> 4;

    f32x4 acc[4][4];
    #pragma unroll
    for (int mt = 0; mt < 4; ++mt)
        #pragma unroll
        for (int nt = 0; nt < 4; ++nt) acc[mt][nt] = (f32x4){0.f, 0.f, 0.f, 0.f};

    for (int chunk = 0; chunk < 4; ++chunk) {
        __syncthreads();
        #pragma unroll
        for (int it = 0; it < 4; ++it) {
            int task = tid + it * 256;
            int r = task >> 4, ch = task & 15;
            *(bf16x8*)&s_a[r][ch * 8] =
                *(const bf16x8*)(z_grp + ((size_t)(b * LL + t0 + r)) * 512 + chunk * 128 + ch * 8);
        }
        __syncthreads();
        bf16x8 bw[4][4];
        #pragma unroll
        for (int nt = 0; nt < 4; ++nt)
            #pragma unroll
            for (int kk = 0; kk < 4; ++kk) {
                int layer = 2 * chunk + (kk >> 1);
                bw[nt][kk] = *(const bf16x8*)(sWb +
                    ((size_t)(layer * SKIPC + 64 * w + 16 * nt + lr)) * H + (kk & 1) * 32 + 8 * lg);
            }
        #pragma unroll
        for (int mt = 0; mt < 4; ++mt) {
            bf16x8 afr[4];
            #pragma unroll
            for (int kk = 0; kk < 4; ++kk)
                afr[kk] = *(const bf16x8*)&s_a[16 * mt + lr][32 * kk + 8 * lg];
            #pragma unroll
            for (int nt = 0; nt < 4; ++nt)
                #pragma unroll
                for (int kk = 0; kk < 4; ++kk)
                    acc[mt][nt] = __builtin_amdgcn_mfma_f32_16x16x32_bf16(afr[kk], bw[nt][kk], acc[mt][nt], 0, 0, 0);
        }
    }
    #pragma unroll
    for (int mt = 0; mt < 4; ++mt)
        #pragma unroll
        for (int nt = 0; nt < 4; ++nt) {
            int s = 64 * w + 16 * nt + lr;
            #pragma unroll
            for (int reg = 0; reg < 4; ++reg) {
                int t = t0 + 16 * mt + 4 * lg + reg;
                float* p = skipS + ((size_t)(b * LL + t)) * SKIPC + s;
                float v = acc[mt][nt][reg];
                if (!G0) v += *p;
                *p = v;
            }
        }
}

// ---------------------------------------------------------------- head ----
__global__ __launch_bounds__(256) void head_mfma(
    const float* __restrict__ skipS, const float* __restrict__ sbsum,
    const short* __restrict__ W1b, const short* __restrict__ W2b,
    float* __restrict__ out)
{
    __shared__ __align__(16) unsigned char smem[128 * 68 * 4];
    short (*s_x)[264] = (short(*)[264])smem;
    float (*s_o)[68]  = (float(*)[68])smem;
    __shared__ float s_red[4][64];
    __shared__ float s_sb[256];

    const int b = blockIdx.y;
    const int t0 = blockIdx.x * 64;
    const int tid = threadIdx.x;
    const int w = tid >> 6;
    const int lane = tid & 63;
    const int lr = lane & 15, lg = lane >> 4;

    s_sb[tid] = sbsum[tid];
    __syncthreads();

    #pragma unroll
    for (int it = 0; it < 16; ++it) {
        int task = tid + it * 256;
        int r = task >> 6, c4 = task & 63;
        f32x4 v = *(const f32x4*)(skipS + ((size_t)(b * LL + t0 + r)) * SKIPC + c4 * 4);
        bf16x4 o;
        #pragma unroll
        for (int j = 0; j < 4; ++j) o[j] = f2b(fmaxf(v[j] + s_sb[c4 * 4 + j], 0.f));
        *(bf16x4*)&s_x[r][c4 * 4] = o;
    }
    __syncthreads();

    f32x4 acc1[4][4];
    #pragma unroll
    for (int mt = 0; mt < 4; ++mt)
        #pragma unroll
        for (int nt = 0; nt < 4; ++nt) acc1[mt][nt] = (f32x4){0.f, 0.f, 0.f, 0.f};
    #pragma unroll
    for (int mt = 0; mt < 4; ++mt) {
        bf16x8 afr[8];
        #pragma unroll
        for (int kk = 0; kk < 8; ++kk)
            afr[kk] = *(const bf16x8*)&s_x[16 * mt + lr][32 * kk + 8 * lg];
        #pragma unroll
        for (int nt = 0; nt < 4; ++nt)
            #pragma unroll
            for (int kk = 0; kk < 8; ++kk) {
                bf16x8 bw = *(const bf16x8*)(W1b + ((size_t)(64 * w + 16 * nt + lr)) * MU1 + 32 * kk + 8 * lg);
                acc1[mt][nt] = __builtin_amdgcn_mfma_f32_16x16x32_bf16(afr[kk], bw, acc1[mt][nt], 0, 0, 0);
            }
    }
    __syncthreads();
    #pragma unroll
    for (int mt = 0; mt < 4; ++mt)
        #pragma unroll
        for (int nt = 0; nt < 4; ++nt)
            #pragma unroll
            for (int reg = 0; reg < 4; ++reg) {
                int tl = 16 * mt + 4 * lg + reg;
                int o = 64 * w + 16 * nt + lr;
                s_x[tl][o] = f2b(fmaxf(acc1[mt][nt][reg], 0.f));
            }
    __syncthreads();

    f32x4 acc2[4][4];
    #pragma unroll
    for (int mt = 0; mt < 4; ++mt)
        #pragma unroll
        for (int nt = 0; nt < 4; ++nt) acc2[mt][nt] = (f32x4){0.f, 0.f, 0.f, 0.f};
    #pragma unroll
    for (int mt = 0; mt < 4; ++mt) {
        bf16x8 afr[8];
        #pragma unroll
        for (int kk = 0; kk < 8; ++kk)
            afr[kk] = *(const bf16x8*)&s_x[16 * mt + lr][32 * kk + 8 * lg];
        #pragma unroll
        for (int nt = 0; nt < 4; ++nt)
            #pragma unroll
            for (int kk = 0; kk < 8; ++kk) {
                bf16x8 bw = *(const bf16x8*)(W2b + ((size_t)(64 * w + 16 * nt + lr)) * MU1 + 32 * kk + 8 * lg);
                acc2[mt][nt] = __builtin_amdgcn_mfma_f32_16x16x32_bf16(afr[kk], bw, acc2[mt][nt], 0, 0, 0);
            }
    }

    float mv[4][4];
    #pragma unroll
    for (int mt = 0; mt < 4; ++mt)
        #pragma unroll
        for (int reg = 0; reg < 4; ++reg) {
            float m = -3.4e38f;
            #pragma unroll
            for (int nt = 0; nt < 4; ++nt) m = fmaxf(m, acc2[mt][nt][reg]);
            #pragma unroll
            for (int off = 1; off <= 8; off <<= 1) m = fmaxf(m, __shfl_xor(m, off));
            int tl = 16 * mt + 4 * lg + reg;
            if (lr == 0) s_red[w][tl] = m;
        }
    __syncthreads();
    #pragma unroll
    for (int mt = 0; mt < 4; ++mt)
        #pragma unroll
        for (int reg = 0; reg < 4; ++reg) {
            int tl = 16 * mt + 4 * lg + reg;
            mv[mt][reg] = fmaxf(fmaxf(s_red[0][tl], s_red[1][tl]), fmaxf(s_red[2][tl], s_red[3][tl]));
        }
    __syncthreads();
    #pragma unroll
    for (int mt = 0; mt < 4; ++mt)
        #pragma unroll
        for (int reg = 0; reg < 4; ++reg) {
            float s = 0.f;
            #pragma unroll
            for (int nt = 0; nt < 4; ++nt) s += __expf(acc2[mt][nt][reg] - mv[mt][reg]);
            #pragma unroll
            for (int off = 1; off <= 8; off <<= 1) s += __shfl_xor(s, off);
            int tl = 16 * mt + 4 * lg + reg;
            if (lr == 0) s_red[w][tl] = s;
        }
    __syncthreads();
    #pragma unroll
    for (int mt = 0; mt < 4; ++mt)
        #pragma unroll
        for (int reg = 0; reg < 4; ++reg) {
            int tl = 16 * mt + 4 * lg + reg;
            float denom = s_red[0][tl] + s_red[1][tl] + s_red[2][tl] + s_red[3][tl];
            mv[mt][reg] = mv[mt][reg] + logf(denom);
        }
    __syncthreads();

    #pragma unroll
    for (int pass = 0; pass < 2; ++pass) {
        if ((w >> 1) == pass) {
            #pragma unroll
            for (int mt = 0; mt < 4; ++mt)
                #pragma unroll
                for (int nt = 0; nt < 4; ++nt)
                    #pragma unroll
                    for (int reg = 0; reg < 4; ++reg) {
                        int ch = 64 * (w & 1) + 16 * nt + lr;
                        int tl = 16 * mt + 4 * lg + reg;
                        s_o[ch][tl] = acc2[mt][nt][reg] - mv[mt][reg];
                    }
        }
        __syncthreads();
        {
            int row = tid >> 1, half = tid & 1;
            float* op = out + ((size_t)(b * MU1 + pass * 128 + row)) * LL + t0 + half * 32;
            #pragma unroll
            for (int k = 0; k < 8; ++k)
                *(f32x4*)(op + 4 * k) = *(const f32x4*)&s_o[row][half * 32 + 4 * k];
        }
        __syncthreads();
    }
}

// -------------------------------------------------------------- launch ----
extern "C" void kernel_launch(void* const* d_in, const int* in_sizes, int n_in,
                              void* d_out, int out_size, void* d_ws, size_t ws_size,
                              hipStream_t stream)
{
    const float* lf      = (const float*)d_in[0];
    const int*   gold    = (const int*)  d_in[1];
    const float* embed_W = (const float*)d_in[2];
    const float* embed_b = (const float*)d_in[3];
    const float* up_W    = (const float*)d_in[4];
    const float* up_b    = (const float*)d_in[5];
    const float* cond_W  = (const float*)d_in[6];
    const float* cond_b  = (const float*)d_in[7];
    const float* dil_W   = (const float*)d_in[8];
    const float* dil_b   = (const float*)d_in[9];
    const float* skip_W  = (const float*)d_in[10];
    const float* skip_b  = (const float*)d_in[11];
    const float* res_W   = (const float*)d_in[12];
    const float* res_b   = (const float*)d_in[13];
    const float* W1      = (const float*)d_in[14];
    const float* W2      = (const float*)d_in[15];
    float* out = (float*)d_out;

    unsigned char* p = (unsigned char*)d_ws;
    short* sigA      = (short*)p; p += (size_t)BB * LL * H * 2;
    short* sigB      = (short*)p; p += (size_t)BB * LL * H * 2;
    short* z_grp     = (short*)p; p += (size_t)BB * LL * 512 * 2;
    float* skipS     = (float*)p; p += (size_t)BB * LL * SKIPC * 4;
    float* condS     = (float*)p; p += (size_t)BB * 256 * NL * H2 * 4;
    short* dil_Wb    = (short*)p; p += (size_t)NL * 2 * H2 * H * 2;
    short* skip_Wb   = (short*)p; p += (size_t)NL * SKIPC * H * 2;
    short* res_Wb    = (short*)p; p += (size_t)(NL - 1) * H * H * 2;
    short* embed_allb= (short*)p; p += (size_t)MU1 * H * 2;
    float* cond_Wt   = (float*)p; p += (size_t)LF * NL * H2 * 4;
    short* W1b       = (short*)p; p += (size_t)MU1 * SKIPC * 2;
    short* W2b       = (short*)p; p += (size_t)MU1 * MU1 * 2;
    float* sbsum     = (float*)p; p += (size_t)SKIPC * 4;

    const int prep_n = NL*2*H2*H + NL*SKIPC*H + (NL-1)*H*H + MU1*H + LF*NL*H2 + MU1*SKIPC + MU1*MU1 + SKIPC;
    prep_kernel<<<(prep_n + 255) / 256, 256, 0, stream>>>(
        dil_W, skip_W, res_W, embed_W, embed_b, cond_W, W1, W2, skip_b,
        dil_Wb, skip_Wb, res_Wb, embed_allb, cond_Wt, W1b, W2b, sbsum);

    embed_kernel<<<(BB * LL * 8 + 255) / 256, 256, 0, stream>>>(gold, embed_allb, sigA);

    cond_kernel<<<dim3(256, 12, BB), 256, 0, stream>>>(lf, up_W, up_b, cond_Wt, cond_b, dil_b, condS);

    const int dil[6] = {1, 2, 4, 8, 16, 32};
    short* si = sigA;
    short* so = sigB;
    dim3 pgrid(LL / 96, BB);   // 200 x 2
    dim3 sgrid(LL / 64, BB);   // 300 x 2
    for (int pp = 0; pp < 12; ++pp) {
        int dA = dil[(2 * pp) % 6];
        int dB = dil[(2 * pp + 1) % 6];
        if (pp == 11)
            pair_mfma<true><<<pgrid, 256, 0, stream>>>(si, so, z_grp, dil_Wb, res_Wb, res_b, condS, pp, dA, dB);
        else
            pair_mfma<false><<<pgrid, 256, 0, stream>>>(si, so, z_grp, dil_Wb, res_Wb, res_b, condS, pp, dA, dB);
        short* tmp = si; si = so; so = tmp;

        if ((pp & 3) == 3) {
            int g = pp >> 2;
            const short* sWb = skip_Wb + (size_t)g * 8 * SKIPC * H;
            if (g == 0)
                skip_gemm<true><<<sgrid, 256, 0, stream>>>(z_grp, sWb, skipS);
            else
                skip_gemm<false><<<sgrid, 256, 0, stream>>>(z_grp, sWb, skipS);
        }
    }

    head_mfma<<<sgrid, 256, 0, stream>>>(skipS, sbsum, W1b, W2b, out);
}

// Round 4
// 559.032 us; speedup vs baseline: 5.0373x; 1.0329x over previous
//
#include <hip/hip_runtime.h>
#include <math.h>

#define MU1   256
#define H     64
#define H2    128
#define SKIPC 256
#define NL    24
#define LF    80
#define UPK   4
#define REP   75
#define BB    2
#define LLEN  64
#define LL    19200

using bf16x8 = __attribute__((ext_vector_type(8))) short;
using bf16x4 = __attribute__((ext_vector_type(4))) short;
using f32x4  = __attribute__((ext_vector_type(4))) float;

__device__ __forceinline__ float b2f(short s) {
    union { unsigned u; float f; } v; v.u = ((unsigned)(unsigned short)s) << 16; return v.f;
}
__device__ __forceinline__ short f2b(float f) {
    union { float f; unsigned u; } v; v.f = f;
    unsigned r = (v.u + 0x7fff + ((v.u >> 16) & 1)) >> 16;
    return (short)r;
}

// ---------------------------------------------------------------- prep ----
__global__ __launch_bounds__(256) void prep_kernel(
    const float* __restrict__ dil_W,  const float* __restrict__ skip_W,
    const float* __restrict__ res_W,  const float* __restrict__ embed_W,
    const float* __restrict__ embed_b,const float* __restrict__ cond_W,
    const float* __restrict__ out_W1, const float* __restrict__ out_W2,
    const float* __restrict__ skip_b,
    short* __restrict__ dil_Wb, short* __restrict__ sWt,
    short* __restrict__ res_Wb, short* __restrict__ embed_allb,
    float* __restrict__ cond_Wt, short* __restrict__ W1b,
    short* __restrict__ W2b, float* __restrict__ sbsum)
{
    int idx = blockIdx.x * 256 + threadIdx.x;
    const int n1 = NL * 2 * H2 * H;     // dil_Wb[i][k][o][c]
    const int n2 = 12 * 256 * 128;      // sWt[ck][s][kc], kc=(sublayer,c)
    const int n3 = (NL - 1) * H * H;    // res_Wb[i][o][c]
    const int n4 = MU1 * H;             // embed_allb[g][h]
    const int n5 = LF * NL * H2;        // cond_Wt[c][o]
    const int n6 = MU1 * SKIPC;
    const int n7 = MU1 * MU1;
    if (idx < n1) {
        int c = idx & 63; int o = (idx >> 6) & 127;
        int k = (idx >> 13) & 1; int i = idx >> 14;
        dil_Wb[idx] = f2b(dil_W[((i * H2 + o) * H + c) * 2 + k]);
        return;
    }
    idx -= n1;
    if (idx < n2) {
        int kc = idx & 127; int s = (idx >> 7) & 255; int ck = idx >> 15;
        sWt[idx] = f2b(skip_W[((2 * ck + (kc >> 6)) * SKIPC + s) * H + (kc & 63)]);
        return;
    }
    idx -= n2;
    if (idx < n3) { res_Wb[idx] = f2b(res_W[idx]); return; }
    idx -= n3;
    if (idx < n4) {
        int h = idx & 63; int g = idx >> 6;
        embed_allb[idx] = f2b(embed_W[h * MU1 + g] + embed_b[h]);
        return;
    }
    idx -= n4;
    if (idx < n5) {
        int o = idx % (NL * H2); int c = idx / (NL * H2);
        cond_Wt[idx] = cond_W[o * LF + c];
        return;
    }
    idx -= n5;
    if (idx < n6) { W1b[idx] = f2b(out_W1[idx]); return; }
    idx -= n6;
    if (idx < n7) { W2b[idx] = f2b(out_W2[idx]); return; }
    idx -= n7;
    if (idx < SKIPC) {
        float a = 0.f;
        for (int i = 0; i < NL; i++) a += skip_b[i * SKIPC + idx];
        sbsum[idx] = a;
        return;
    }
}

// --------------------------------------------------------------- embed ----
__global__ __launch_bounds__(256) void embed_kernel(
    const int* __restrict__ gold, const short* __restrict__ eW,
    short* __restrict__ sig)
{
    int idx = blockIdx.x * 256 + threadIdx.x;
    if (idx >= BB * LL * 8) return;
    int ch = idx & 7; int bt = idx >> 3;
    int g = gold[bt];
    *(bf16x8*)(sig + (size_t)bt * H + ch * 8) = *(const bf16x8*)(eW + g * H + ch * 8);
}

// ---------------------------------------------------------------- cond ----
__global__ __launch_bounds__(256) void cond_kernel(
    const float* __restrict__ lf, const float* __restrict__ up_W,
    const float* __restrict__ up_b, const float* __restrict__ cond_Wt,
    const float* __restrict__ cond_b, const float* __restrict__ dil_b,
    float* __restrict__ condS)
{
    __shared__ float s_up[LF];
    int j = blockIdx.x;
    int ot = blockIdx.y;
    int b = blockIdx.z;
    int frame = j >> 2, k = j & 3;
    int tid = threadIdx.x;
    if (tid < LF) {
        float a = up_b[tid];
        const float* lfr = lf + (b * LLEN + frame) * LF;
        #pragma unroll 8
        for (int c = 0; c < LF; ++c) a += lfr[c] * up_W[(c * LF + tid) * UPK + k];
        s_up[tid] = a;
    }
    __syncthreads();
    int o = ot * 256 + tid;
    float a = cond_b[o] + dil_b[o];
    #pragma unroll 8
    for (int c = 0; c < LF; ++c) a += cond_Wt[c * 3072 + o] * s_up[c];
    condS[((size_t)(b * 256 + j)) * 3072 + o] = a;
}

// ---------------------------------------------------- fused layer pair ----
template<int DA, int DB, bool LASTPAIR>
__global__ __launch_bounds__(256) void pair_mfma(
    const short* __restrict__ sig_in, short* __restrict__ sig_out,
    short* __restrict__ z12,
    const short* __restrict__ dil_Wb_all,
    const short* __restrict__ res_Wb_all,
    const float* __restrict__ res_b_all,
    const float* __restrict__ condS,
    int p, int slot)
{
    __shared__ __align__(16) short sa[144][72];   // input rows [t0-48, t0+96)
    __shared__ __align__(16) short sb[128][72];   // A output rows [t0-32, t0+96)
    __shared__ __align__(16) short sz[128][72];   // z scratch
    __shared__ float scond[2][3][128];

    const int iA = 2 * p, iB = 2 * p + 1;
    const int b = blockIdx.y;
    const int t0 = blockIdx.x * 96;
    const int tid = threadIdx.x;
    const int w = tid >> 6;
    const int lane = tid & 63;
    const int lr = lane & 15, lg = lane >> 4;
    const int c0 = (t0 >= 32) ? (t0 - 32) / 75 : 0;

    // ---- stage input + cond ----
    {
        const short* basein = sig_in + (size_t)b * LL * H;
        #pragma unroll
        for (int it = 0; it < 5; ++it) {
            int task = tid + it * 256;
            if (task < 1152) {
                int r = task >> 3, ch = task & 7;
                int t = t0 - 48 + r;
                bf16x8 v = {};
                if (t >= 0) v = *(const bf16x8*)(basein + (size_t)t * H + ch * 8);
                *(bf16x8*)&sa[r][ch * 8] = v;
            }
        }
        #pragma unroll
        for (int it = 0; it < 3; ++it) {
            int task = tid + it * 256;      // 768 = 2 sel x 3 col x 128
            int sel = task >= 384;
            int cj = (task - sel * 384) >> 7;
            int o = task & 127;
            int col = c0 + cj; col = col > 255 ? 255 : col;
            scond[sel][cj][o] = condS[((size_t)(b * 256 + col)) * 3072 + (iA + sel) * 128 + o];
        }
    }
    __syncthreads();

    // ---- A gated GEMM: M=128 (2 Mtiles/wave), N=128, K=128 ----
    {
        const short* dW = dil_Wb_all + (size_t)iA * 2 * H2 * H;
        f32x4 acc[2][8];
        #pragma unroll
        for (int m = 0; m < 2; ++m)
            #pragma unroll
            for (int n = 0; n < 8; ++n) acc[m][n] = (f32x4){0.f, 0.f, 0.f, 0.f};
        bf16x8 afA[2][4];
        #pragma unroll
        for (int m = 0; m < 2; ++m) {
            int rc = 16 + 16 * (2 * w + m) + lr;
            afA[m][0] = *(const bf16x8*)&sa[rc - DA][lg * 8];
            afA[m][1] = *(const bf16x8*)&sa[rc - DA][32 + lg * 8];
            afA[m][2] = *(const bf16x8*)&sa[rc][lg * 8];
            afA[m][3] = *(const bf16x8*)&sa[rc][32 + lg * 8];
        }
        #pragma unroll
        for (int n = 0; n < 8; ++n)
            #pragma unroll
            for (int kk = 0; kk < 4; ++kk) {
                bf16x8 bw = *(const bf16x8*)(dW + (((kk >> 1) * H2 + 16 * n + lr) * H) + (kk & 1) * 32 + lg * 8);
                acc[0][n] = __builtin_amdgcn_mfma_f32_16x16x32_bf16(afA[0][kk], bw, acc[0][n], 0, 0, 0);
                acc[1][n] = __builtin_amdgcn_mfma_f32_16x16x32_bf16(afA[1][kk], bw, acc[1][n], 0, 0, 0);
            }
        #pragma unroll
        for (int m = 0; m < 2; ++m)
            #pragma unroll
            for (int n = 0; n < 4; ++n)
                #pragma unroll
                for (int r = 0; r < 4; ++r) {
                    int relt = -32 + 16 * (2 * w + m) + 4 * lg + r;
                    int t = t0 + relt;
                    int o = 16 * n + lr;
                    short zb = 0;
                    if (t >= 0) {
                        int ci = t / 75 - c0;
                        float av = acc[m][n][r] + scond[0][ci][o];
                        float gv = acc[m][n + 4][r] + scond[0][ci][64 + o];
                        float th = 1.f - 2.f / (__expf(2.f * av) + 1.f);
                        float sg = 1.f / (1.f + __expf(-gv));
                        zb = f2b(th * sg);
                    }
                    sz[relt + 32][o] = zb;
                }
    }
    __syncthreads();

    // z_A -> z12 slot, sub 0 (rows [0,96))
    #pragma unroll
    for (int it = 0; it < 3; ++it) {
        int task = tid + it * 256;
        int r = task >> 3, ch = task & 7;
        *(bf16x8*)(z12 + ((size_t)((slot * BB + b) * LL) + t0 + r) * 128 + ch * 8)
            = *(const bf16x8*)&sz[32 + r][ch * 8];
    }

    // ---- A residual: sb = sa + z @ rW + rb ----
    {
        const short* rW = res_Wb_all + (size_t)iA * H * H;
        const float* rb_ = res_b_all + (size_t)iA * H;
        f32x4 rac[2][4];
        #pragma unroll
        for (int m = 0; m < 2; ++m)
            #pragma unroll
            for (int n = 0; n < 4; ++n) rac[m][n] = (f32x4){0.f, 0.f, 0.f, 0.f};
        bf16x8 za[2][2];
        #pragma unroll
        for (int m = 0; m < 2; ++m) {
            int row = 16 * (2 * w + m) + lr;
            za[m][0] = *(const bf16x8*)&sz[row][lg * 8];
            za[m][1] = *(const bf16x8*)&sz[row][32 + lg * 8];
        }
        #pragma unroll
        for (int n = 0; n < 4; ++n)
            #pragma unroll
            for (int kk = 0; kk < 2; ++kk) {
                bf16x8 bw = *(const bf16x8*)(rW + (16 * n + lr) * H + kk * 32 + lg * 8);
                rac[0][n] = __builtin_amdgcn_mfma_f32_16x16x32_bf16(za[0][kk], bw, rac[0][n], 0, 0, 0);
                rac[1][n] = __builtin_amdgcn_mfma_f32_16x16x32_bf16(za[1][kk], bw, rac[1][n], 0, 0, 0);
            }
        #pragma unroll
        for (int n = 0; n < 4; ++n) {
            float rbv = rb_[16 * n + lr];
            #pragma unroll
            for (int m = 0; m < 2; ++m)
                #pragma unroll
                for (int r = 0; r < 4; ++r) {
                    int relt = -32 + 16 * (2 * w + m) + 4 * lg + r;
                    int t = t0 + relt;
                    int c = 16 * n + lr;
                    short vb = 0;
                    if (t >= 0) vb = f2b(b2f(sa[relt + 48][c]) + rac[m][n][r] + rbv);
                    sb[relt + 32][c] = vb;
                }
        }
    }
    __syncthreads();

    // ---- B gated GEMM: M=96 (6 Mtiles), wave w -> out channels (w, w+4) ----
    {
        const short* dW = dil_Wb_all + (size_t)iB * 2 * H2 * H;
        f32x4 accF[6], accG[6];
        #pragma unroll
        for (int m = 0; m < 6; ++m) { accF[m] = (f32x4){0.f,0.f,0.f,0.f}; accG[m] = (f32x4){0.f,0.f,0.f,0.f}; }
        bf16x8 bwF[4], bwG[4];
        #pragma unroll
        for (int kk = 0; kk < 4; ++kk) {
            int oF = 16 * w + lr;
            bwF[kk] = *(const bf16x8*)(dW + (((kk >> 1) * H2 + oF) * H) + (kk & 1) * 32 + lg * 8);
            bwG[kk] = *(const bf16x8*)(dW + (((kk >> 1) * H2 + 64 + oF) * H) + (kk & 1) * 32 + lg * 8);
        }
        #pragma unroll
        for (int m = 0; m < 6; ++m) {
            int rc = 32 + 16 * m + lr;
            bf16x8 af[4];
            af[0] = *(const bf16x8*)&sb[rc - DB][lg * 8];
            af[1] = *(const bf16x8*)&sb[rc - DB][32 + lg * 8];
            af[2] = *(const bf16x8*)&sb[rc][lg * 8];
            af[3] = *(const bf16x8*)&sb[rc][32 + lg * 8];
            #pragma unroll
            for (int kk = 0; kk < 4; ++kk)
                accF[m] = __builtin_amdgcn_mfma_f32_16x16x32_bf16(af[kk], bwF[kk], accF[m], 0, 0, 0);
            #pragma unroll
            for (int kk = 0; kk < 4; ++kk)
                accG[m] = __builtin_amdgcn_mfma_f32_16x16x32_bf16(af[kk], bwG[kk], accG[m], 0, 0, 0);
        }
        #pragma unroll
        for (int m = 0; m < 6; ++m)
            #pragma unroll
            for (int r = 0; r < 4; ++r) {
                int relt = 16 * m + 4 * lg + r;
                int t = t0 + relt;
                int o = 16 * w + lr;
                int ci = t / 75 - c0;
                float av = accF[m][r] + scond[1][ci][o];
                float gv = accG[m][r] + scond[1][ci][64 + o];
                float th = 1.f - 2.f / (__expf(2.f * av) + 1.f);
                float sg = 1.f / (1.f + __expf(-gv));
                sz[relt][o] = f2b(th * sg);
            }
    }
    __syncthreads();

    // z_B -> z12 slot, sub 1 (rows [0,96))
    #pragma unroll
    for (int it = 0; it < 3; ++it) {
        int task = tid + it * 256;
        int r = task >> 3, ch = task & 7;
        *(bf16x8*)(z12 + ((size_t)((slot * BB + b) * LL) + t0 + r) * 128 + 64 + ch * 8)
            = *(const bf16x8*)&sz[r][ch * 8];
    }

    // ---- B residual -> sig_out (rows [0,96)), wave w -> Ntile w ----
    if (!LASTPAIR) {
        const short* rW = res_Wb_all + (size_t)iB * H * H;
        const float* rb_ = res_b_all + (size_t)iB * H;
        int c = 16 * w + lr;
        f32x4 rac[6];
        #pragma unroll
        for (int m = 0; m < 6; ++m) rac[m] = (f32x4){0.f, 0.f, 0.f, 0.f};
        bf16x8 bwR[2];
        bwR[0] = *(const bf16x8*)(rW + c * H + lg * 8);
        bwR[1] = *(const bf16x8*)(rW + c * H + 32 + lg * 8);
        #pragma unroll
        for (int m = 0; m < 6; ++m) {
            bf16x8 z0 = *(const bf16x8*)&sz[16 * m + lr][lg * 8];
            bf16x8 z1 = *(const bf16x8*)&sz[16 * m + lr][32 + lg * 8];
            rac[m] = __builtin_amdgcn_mfma_f32_16x16x32_bf16(z0, bwR[0], rac[m], 0, 0, 0);
            rac[m] = __builtin_amdgcn_mfma_f32_16x16x32_bf16(z1, bwR[1], rac[m], 0, 0, 0);
        }
        float rbv = rb_[c];
        #pragma unroll
        for (int m = 0; m < 6; ++m)
            #pragma unroll
            for (int r = 0; r < 4; ++r) {
                int relt = 16 * m + 4 * lg + r;
                sa[relt][c] = f2b(b2f(sb[relt + 32][c]) + rac[m][r] + rbv);
            }
        __syncthreads();
        #pragma unroll
        for (int it = 0; it < 3; ++it) {
            int task = tid + it * 256;
            int r = task >> 3, ch = task & 7;
            *(bf16x8*)(sig_out + ((size_t)(b * LL + t0 + r)) * H + ch * 8)
                = *(const bf16x8*)&sa[r][ch * 8];
        }
    }
}

// -------------------------------------------------- skip (layers 0-11) ----
__global__ __launch_bounds__(256) void skip12_kernel(
    const short* __restrict__ z12, const short* __restrict__ sWt,
    short* __restrict__ skipP)
{
    __shared__ __align__(16) short s_a[2][64][136];
    const int b = blockIdx.y;
    const int t0 = blockIdx.x * 64;
    const int tid = threadIdx.x;
    const int w = tid >> 6;
    const int lane = tid & 63;
    const int lr = lane & 15, lg = lane >> 4;

    f32x4 acc[4][4];
    #pragma unroll
    for (int mt = 0; mt < 4; ++mt)
        #pragma unroll
        for (int nt = 0; nt < 4; ++nt) acc[mt][nt] = (f32x4){0.f, 0.f, 0.f, 0.f};

    // stage slot 0
    #pragma unroll
    for (int it = 0; it < 4; ++it) {
        int task = tid + it * 256;
        int r = task >> 4, ch = task & 15;
        *(bf16x8*)&s_a[0][r][ch * 8] =
            *(const bf16x8*)(z12 + ((size_t)(b * LL) + t0 + r) * 128 + ch * 8);
    }
    __syncthreads();

    for (int ck = 0; ck < 6; ++ck) {
        if (ck < 5) {
            #pragma unroll
            for (int it = 0; it < 4; ++it) {
                int task = tid + it * 256;
                int r = task >> 4, ch = task & 15;
                *(bf16x8*)&s_a[(ck + 1) & 1][r][ch * 8] =
                    *(const bf16x8*)(z12 + ((size_t)(((ck + 1) * BB + b) * LL) + t0 + r) * 128 + ch * 8);
            }
        }
        const short* wbase = sWt + ((size_t)ck << 15);
        const short (*buf)[136] = s_a[ck & 1];
        #pragma unroll
        for (int kk = 0; kk < 4; ++kk) {
            bf16x8 afr[4];
            #pragma unroll
            for (int mt = 0; mt < 4; ++mt)
                afr[mt] = *(const bf16x8*)&buf[16 * mt + lr][32 * kk + 8 * lg];
            #pragma unroll
            for (int nt = 0; nt < 4; ++nt) {
                bf16x8 bw = *(const bf16x8*)(wbase + ((64 * w + 16 * nt + lr) << 7) + 32 * kk + 8 * lg);
                #pragma unroll
                for (int mt = 0; mt < 4; ++mt)
                    acc[mt][nt] = __builtin_amdgcn_mfma_f32_16x16x32_bf16(afr[mt], bw, acc[mt][nt], 0, 0, 0);
            }
        }
        __syncthreads();
    }

    #pragma unroll
    for (int mt = 0; mt < 4; ++mt)
        #pragma unroll
        for (int nt = 0; nt < 4; ++nt) {
            int s = 64 * w + 16 * nt + lr;
            #pragma unroll
            for (int reg = 0; reg < 4; ++reg) {
                int t = t0 + 16 * mt + 4 * lg + reg;
                skipP[((size_t)(b * LL) + t) * 256 + s] = f2b(acc[mt][nt][reg]);
            }
        }
}

// --------------------------------- fused skip (12-23) + output head ----
__global__ __launch_bounds__(256) void skiphead_kernel(
    const short* __restrict__ z12, const short* __restrict__ sWt,
    const short* __restrict__ skipP, const float* __restrict__ sbsum,
    const short* __restrict__ W1b, const short* __restrict__ W2b,
    float* __restrict__ out)
{
    __shared__ __align__(16) unsigned char smem[36864];
    short (*s_ab)[64][136] = (short(*)[64][136])smem;   // dbuf z tiles (phase S)
    short (*s_x)[264] = (short(*)[264])smem;            // 64x264 bf16 (head)
    float (*s_o)[68]  = (float(*)[68])smem;             // 128x68 f32 (out transpose)
    __shared__ float s_red[4][64];
    __shared__ float s_sb[256];

    const int b = blockIdx.y;
    const int t0 = blockIdx.x * 64;
    const int tid = threadIdx.x;
    const int w = tid >> 6;
    const int lane = tid & 63;
    const int lr = lane & 15, lg = lane >> 4;

    s_sb[tid] = sbsum[tid];

    f32x4 acc[4][4];
    #pragma unroll
    for (int mt = 0; mt < 4; ++mt)
        #pragma unroll
        for (int nt = 0; nt < 4; ++nt) acc[mt][nt] = (f32x4){0.f, 0.f, 0.f, 0.f};

    // ---- phase S: skip GEMM for layers 12..23 (slots 0..5, chunks 6..11) ----
    #pragma unroll
    for (int it = 0; it < 4; ++it) {
        int task = tid + it * 256;
        int r = task >> 4, ch = task & 15;
        *(bf16x8*)&s_ab[0][r][ch * 8] =
            *(const bf16x8*)(z12 + ((size_t)(b * LL) + t0 + r) * 128 + ch * 8);
    }
    __syncthreads();
    for (int ck = 0; ck < 6; ++ck) {
        if (ck < 5) {
            #pragma unroll
            for (int it = 0; it < 4; ++it) {
                int task = tid + it * 256;
                int r = task >> 4, ch = task & 15;
                *(bf16x8*)&s_ab[(ck + 1) & 1][r][ch * 8] =
                    *(const bf16x8*)(z12 + ((size_t)(((ck + 1) * BB + b) * LL) + t0 + r) * 128 + ch * 8);
            }
        }
        const short* wbase = sWt + ((size_t)(6 + ck) << 15);
        const short (*buf)[136] = s_ab[ck & 1];
        #pragma unroll
        for (int kk = 0; kk < 4; ++kk) {
            bf16x8 afr[4];
            #pragma unroll
            for (int mt = 0; mt < 4; ++mt)
                afr[mt] = *(const bf16x8*)&buf[16 * mt + lr][32 * kk + 8 * lg];
            #pragma unroll
            for (int nt = 0; nt < 4; ++nt) {
                bf16x8 bw = *(const bf16x8*)(wbase + ((64 * w + 16 * nt + lr) << 7) + 32 * kk + 8 * lg);
                #pragma unroll
                for (int mt = 0; mt < 4; ++mt)
                    acc[mt][nt] = __builtin_amdgcn_mfma_f32_16x16x32_bf16(afr[mt], bw, acc[mt][nt], 0, 0, 0);
            }
        }
        __syncthreads();
    }

    // ---- stage bf16 partial (layers 0-11) and fold: x = relu(p + acc + sb) ----
    #pragma unroll
    for (int it = 0; it < 8; ++it) {
        int task = tid + it * 256;
        int r = task >> 5, ch = task & 31;
        *(bf16x8*)&s_x[r][ch * 8] =
            *(const bf16x8*)(skipP + ((size_t)(b * LL) + t0 + r) * 256 + ch * 8);
    }
    __syncthreads();
    #pragma unroll
    for (int mt = 0; mt < 4; ++mt)
        #pragma unroll
        for (int nt = 0; nt < 4; ++nt) {
            int s = 64 * w + 16 * nt + lr;
            #pragma unroll
            for (int reg = 0; reg < 4; ++reg) {
                int tl = 16 * mt + 4 * lg + reg;
                float v = acc[mt][nt][reg] + b2f(s_x[tl][s]) + s_sb[s];
                s_x[tl][s] = f2b(fmaxf(v, 0.f));
            }
        }
    __syncthreads();

    // ---- GEMM1: h = relu(x @ W1^T), kk-outer (each bw loaded once) ----
    f32x4 acc1[4][4];
    #pragma unroll
    for (int mt = 0; mt < 4; ++mt)
        #pragma unroll
        for (int nt = 0; nt < 4; ++nt) acc1[mt][nt] = (f32x4){0.f, 0.f, 0.f, 0.f};
    #pragma unroll
    for (int kk = 0; kk < 8; ++kk) {
        bf16x8 afr[4];
        #pragma unroll
        for (int mt = 0; mt < 4; ++mt)
            afr[mt] = *(const bf16x8*)&s_x[16 * mt + lr][32 * kk + 8 * lg];
        #pragma unroll
        for (int nt = 0; nt < 4; ++nt) {
            bf16x8 bw = *(const bf16x8*)(W1b + ((size_t)(64 * w + 16 * nt + lr)) * MU1 + 32 * kk + 8 * lg);
            #pragma unroll
            for (int mt = 0; mt < 4; ++mt)
                acc1[mt][nt] = __builtin_amdgcn_mfma_f32_16x16x32_bf16(afr[mt], bw, acc1[mt][nt], 0, 0, 0);
        }
    }
    __syncthreads();
    #pragma unroll
    for (int mt = 0; mt < 4; ++mt)
        #pragma unroll
        for (int nt = 0; nt < 4; ++nt)
            #pragma unroll
            for (int reg = 0; reg < 4; ++reg) {
                int tl = 16 * mt + 4 * lg + reg;
                int o = 64 * w + 16 * nt + lr;
                s_x[tl][o] = f2b(fmaxf(acc1[mt][nt][reg], 0.f));
            }
    __syncthreads();

    // ---- GEMM2: logits ----
    f32x4 acc2[4][4];
    #pragma unroll
    for (int mt = 0; mt < 4; ++mt)
        #pragma unroll
        for (int nt = 0; nt < 4; ++nt) acc2[mt][nt] = (f32x4){0.f, 0.f, 0.f, 0.f};
    #pragma unroll
    for (int kk = 0; kk < 8; ++kk) {
        bf16x8 afr[4];
        #pragma unroll
        for (int mt = 0; mt < 4; ++mt)
            afr[mt] = *(const bf16x8*)&s_x[16 * mt + lr][32 * kk + 8 * lg];
        #pragma unroll
        for (int nt = 0; nt < 4; ++nt) {
            bf16x8 bw = *(const bf16x8*)(W2b + ((size_t)(64 * w + 16 * nt + lr)) * MU1 + 32 * kk + 8 * lg);
            #pragma unroll
            for (int mt = 0; mt < 4; ++mt)
                acc2[mt][nt] = __builtin_amdgcn_mfma_f32_16x16x32_bf16(afr[mt], bw, acc2[mt][nt], 0, 0, 0);
        }
    }

    // ---- log-softmax over 256 channels ----
    float mv[4][4];
    #pragma unroll
    for (int mt = 0; mt < 4; ++mt)
        #pragma unroll
        for (int reg = 0; reg < 4; ++reg) {
            float m = -3.4e38f;
            #pragma unroll
            for (int nt = 0; nt < 4; ++nt) m = fmaxf(m, acc2[mt][nt][reg]);
            #pragma unroll
            for (int off = 1; off <= 8; off <<= 1) m = fmaxf(m, __shfl_xor(m, off));
            int tl = 16 * mt + 4 * lg + reg;
            if (lr == 0) s_red[w][tl] = m;
        }
    __syncthreads();
    #pragma unroll
    for (int mt = 0; mt < 4; ++mt)
        #pragma unroll
        for (int reg = 0; reg < 4; ++reg) {
            int tl = 16 * mt + 4 * lg + reg;
            mv[mt][reg] = fmaxf(fmaxf(s_red[0][tl], s_red[1][tl]), fmaxf(s_red[2][tl], s_red[3][tl]));
        }
    __syncthreads();
    #pragma unroll
    for (int mt = 0; mt < 4; ++mt)
        #pragma unroll
        for (int reg = 0; reg < 4; ++reg) {
            float s = 0.f;
            #pragma unroll
            for (int nt = 0; nt < 4; ++nt) s += __expf(acc2[mt][nt][reg] - mv[mt][reg]);
            #pragma unroll
            for (int off = 1; off <= 8; off <<= 1) s += __shfl_xor(s, off);
            int tl = 16 * mt + 4 * lg + reg;
            if (lr == 0) s_red[w][tl] = s;
        }
    __syncthreads();
    #pragma unroll
    for (int mt = 0; mt < 4; ++mt)
        #pragma unroll
        for (int reg = 0; reg < 4; ++reg) {
            int tl = 16 * mt + 4 * lg + reg;
            float denom = s_red[0][tl] + s_red[1][tl] + s_red[2][tl] + s_red[3][tl];
            mv[mt][reg] = mv[mt][reg] + __logf(denom);
        }
    __syncthreads();

    // ---- transposed store via LDS ----
    #pragma unroll
    for (int pass = 0; pass < 2; ++pass) {
        if ((w >> 1) == pass) {
            #pragma unroll
            for (int mt = 0; mt < 4; ++mt)
                #pragma unroll
                for (int nt = 0; nt < 4; ++nt)
                    #pragma unroll
                    for (int reg = 0; reg < 4; ++reg) {
                        int ch = 64 * (w & 1) + 16 * nt + lr;
                        int tl = 16 * mt + 4 * lg + reg;
                        s_o[ch][tl] = acc2[mt][nt][reg] - mv[mt][reg];
                    }
        }
        __syncthreads();
        {
            int row = tid >> 1, half = tid & 1;
            float* op = out + ((size_t)(b * MU1 + pass * 128 + row)) * LL + t0 + half * 32;
            #pragma unroll
            for (int k = 0; k < 8; ++k)
                *(f32x4*)(op + 4 * k) = *(const f32x4*)&s_o[row][half * 32 + 4 * k];
        }
        __syncthreads();
    }
}

// -------------------------------------------------------------- launch ----
extern "C" void kernel_launch(void* const* d_in, const int* in_sizes, int n_in,
                              void* d_out, int out_size, void* d_ws, size_t ws_size,
                              hipStream_t stream)
{
    const float* lf      = (const float*)d_in[0];
    const int*   gold    = (const int*)  d_in[1];
    const float* embed_W = (const float*)d_in[2];
    const float* embed_b = (const float*)d_in[3];
    const float* up_W    = (const float*)d_in[4];
    const float* up_b    = (const float*)d_in[5];
    const float* cond_W  = (const float*)d_in[6];
    const float* cond_b  = (const float*)d_in[7];
    const float* dil_W   = (const float*)d_in[8];
    const float* dil_b   = (const float*)d_in[9];
    const float* skip_W  = (const float*)d_in[10];
    const float* skip_b  = (const float*)d_in[11];
    const float* res_W   = (const float*)d_in[12];
    const float* res_b   = (const float*)d_in[13];
    const float* W1      = (const float*)d_in[14];
    const float* W2      = (const float*)d_in[15];
    float* out = (float*)d_out;

    unsigned char* p = (unsigned char*)d_ws;
    short* sigA      = (short*)p; p += (size_t)BB * LL * H * 2;          // 4.9 MB
    short* sigB      = (short*)p; p += (size_t)BB * LL * H * 2;          // 4.9 MB
    short* z12       = (short*)p; p += (size_t)6 * BB * LL * 128 * 2;    // 59 MB
    short* skipP     = (short*)p; p += (size_t)BB * LL * SKIPC * 2;      // 19.7 MB
    float* condS     = (float*)p; p += (size_t)BB * 256 * NL * H2 * 4;   // 6.3 MB
    short* dil_Wb    = (short*)p; p += (size_t)NL * 2 * H2 * H * 2;
    short* sWt       = (short*)p; p += (size_t)12 * 256 * 128 * 2;
    short* res_Wb    = (short*)p; p += (size_t)(NL - 1) * H * H * 2;
    short* embed_allb= (short*)p; p += (size_t)MU1 * H * 2;
    float* cond_Wt   = (float*)p; p += (size_t)LF * NL * H2 * 4;
    short* W1b       = (short*)p; p += (size_t)MU1 * SKIPC * 2;
    short* W2b       = (short*)p; p += (size_t)MU1 * MU1 * 2;
    float* sbsum     = (float*)p; p += (size_t)SKIPC * 4;

    const int prep_n = NL*2*H2*H + 12*256*128 + (NL-1)*H*H + MU1*H + LF*NL*H2 + MU1*SKIPC + MU1*MU1 + SKIPC;
    prep_kernel<<<(prep_n + 255) / 256, 256, 0, stream>>>(
        dil_W, skip_W, res_W, embed_W, embed_b, cond_W, W1, W2, skip_b,
        dil_Wb, sWt, res_Wb, embed_allb, cond_Wt, W1b, W2b, sbsum);

    embed_kernel<<<(BB * LL * 8 + 255) / 256, 256, 0, stream>>>(gold, embed_allb, sigA);

    cond_kernel<<<dim3(256, 12, BB), 256, 0, stream>>>(lf, up_W, up_b, cond_Wt, cond_b, dil_b, condS);

    short* si = sigA;
    short* so = sigB;
    dim3 pgrid(LL / 96, BB);   // 200 x 2
    dim3 sgrid(LL / 64, BB);   // 300 x 2
    for (int pp = 0; pp < 12; ++pp) {
        int slot = pp % 6;
        int r3 = pp % 3;
        if (r3 == 0)
            pair_mfma<1, 2, false><<<pgrid, 256, 0, stream>>>(si, so, z12, dil_Wb, res_Wb, res_b, condS, pp, slot);
        else if (r3 == 1)
            pair_mfma<4, 8, false><<<pgrid, 256, 0, stream>>>(si, so, z12, dil_Wb, res_Wb, res_b, condS, pp, slot);
        else if (pp == 11)
            pair_mfma<16, 32, true><<<pgrid, 256, 0, stream>>>(si, so, z12, dil_Wb, res_Wb, res_b, condS, pp, slot);
        else
            pair_mfma<16, 32, false><<<pgrid, 256, 0, stream>>>(si, so, z12, dil_Wb, res_Wb, res_b, condS, pp, slot);
        short* tmp = si; si = so; so = tmp;

        if (pp == 5)
            skip12_kernel<<<sgrid, 256, 0, stream>>>(z12, sWt, skipP);
    }

    skiphead_kernel<<<sgrid, 256, 0, stream>>>(z12, sWt, skipP, sbsum, W1b, W2b, out);
}